// Round 11
// baseline (234.853 us; speedup 1.0000x reference)
//
#include <hip/hip_runtime.h>

#define NNODES 50000
#define NEG 0.01f
#define BN_EPS 1e-5f

#define BINSZ 64             // dst nodes per bin
#define NBINS 782            // ceil(50000/64)
#define CAPG 4096            // record capacity per bin (mean ~2046)
#define PH1B 256             // phase-1 blocks (1 per CU)
#define RING 32              // ring slots per bin (flush granule 16)
#define NTILE 7              // src tiles of 8192 nodes (tile = src>>13)
#define NKEY (NTILE * 64)    // 448 sort keys

typedef __attribute__((ext_vector_type(8))) short bf16x8;
typedef __attribute__((ext_vector_type(4))) float f32x4;

__device__ __forceinline__ float lrelu(float v) { return v >= 0.f ? v : NEG * v; }
__device__ __forceinline__ float bf_lo(unsigned u) { return __uint_as_float(u << 16); }
__device__ __forceinline__ float bf_hi(unsigned u) { return __uint_as_float(u & 0xffff0000u); }
__device__ __forceinline__ unsigned f2bf(float x) {          // RNE
    unsigned u = __float_as_uint(x);
    return (u + 0x7fffu + ((u >> 16) & 1u)) >> 16;
}
__device__ __forceinline__ unsigned packbf(float lo, float hi) {
    unsigned b = __float_as_uint(hi);
    b = (b + 0x7fffu + ((b >> 16) & 1u)) & 0xffff0000u;
    return (f2bf(lo) & 0xffffu) | b;
}
__device__ __forceinline__ void acc8(float* c, uint4 q) {
    c[0] += bf_lo(q.x); c[1] += bf_hi(q.x);
    c[2] += bf_lo(q.y); c[3] += bf_hi(q.y);
    c[4] += bf_lo(q.z); c[5] += bf_hi(q.z);
    c[6] += bf_lo(q.w); c[7] += bf_hi(q.w);
}

// ---------------- 0. convert x + weights to bf16 ----------------
__global__ __launch_bounds__(256)
void prep_kernel(const float* __restrict__ x, const float* __restrict__ Wrel,
                 const float* __restrict__ Wroot, const float* __restrict__ Wlin,
                 unsigned* __restrict__ xb2, unsigned* __restrict__ wb2)
{
    const int NPX = 3200000;           // float pairs in x
    const int NPW = 24576;             // float pairs in 3 weight mats
    for (int i = blockIdx.x * 256 + threadIdx.x; i < NPX + NPW; i += gridDim.x * 256) {
        if (i < NPX) {
            float2 v = ((const float2*)x)[i];
            xb2[i] = packbf(v.x, v.y);
        } else {
            int j = i - NPX;
            const float* W = (j < 8192) ? Wrel : (j < 16384 ? Wroot : Wlin);
            float2 v = ((const float2*)W)[j & 8191];
            wb2[j] = packbf(v.x, v.y);
        }
    }
}

// ---------------- 1. multisplit: bin edges by dst>>6, line-combined flushes ----------------
__global__ __launch_bounds__(256)
void bin_kernel(const int* __restrict__ src, const int* __restrict__ dst,
                int* __restrict__ bcnt, unsigned* __restrict__ recs, int n_edges)
{
    __shared__ __align__(16) unsigned buf[NBINS][RING];   // 100 KB (grid=1/CU: free)
    __shared__ int cnt[NBINS];
    __shared__ int flushed[NBINS];

    const int tid = threadIdx.x;
    for (int t = tid; t < NBINS; t += 256) { cnt[t] = 0; flushed[t] = 0; }
    __syncthreads();

    const int per = (n_edges + PH1B - 1) / PH1B;
    const int begin = blockIdx.x * per;
    const int end = min(begin + per, n_edges);

    for (int base = begin; base < end; base += 256) {
        int i = base + tid;
        if (i < end) {
            int s = src[i], d = dst[i];
            int b = d >> 6;
            unsigned rec = (unsigned)s | ((unsigned)(d & 63) << 16);
            int pos = atomicAdd(&cnt[b], 1);
            buf[b][pos & (RING - 1)] = rec;
        }
        __syncthreads();
        for (int t = tid; t < NBINS; t += 256) {
            int c = cnt[t];
            int f = flushed[t];
            while (c - f >= 16) {                    // 16 recs = 64B = 1 line
                int gbase = atomicAdd(&bcnt[t], 16);
                unsigned* dp = recs + (long)t * CAPG + gbase;
                int ro = f & (RING - 1);             // multiple of 16, no wrap
                #pragma unroll
                for (int k = 0; k < 4; ++k)
                    *(uint4*)(dp + k * 4) = *(uint4*)&buf[t][ro + k * 4];
                f += 16;
            }
            flushed[t] = f;
        }
        __syncthreads();
    }
    for (int t = tid; t < NBINS; t += 256) {
        int c = cnt[t], f = flushed[t];
        int n = c - f;
        if (n > 0) {
            int gbase = atomicAdd(&bcnt[t], n);
            unsigned* dp = recs + (long)t * CAPG + gbase;
            int ro = f & (RING - 1);
            for (int k = 0; k < n; ++k) dp[k] = buf[t][ro + k];
        }
    }
}

// ---------------- 2. FUSED per-bin aggregate (src-tiled) + MLP + BN ----------------
// Records counting-sorted by key = tile*64 + localdst (tile = src>>13). The
// gather sweeps tiles in order; all blocks sweep together (grid ~1 round), so
// each 2.05 MB src tile is L2-resident during its phase. Per-(tile,dst) runs
// register-accumulate, then non-atomic LDS fp32 add (dst owned by one wave).
__global__ __launch_bounds__(512, 3)
void agg_mlp_kernel(const unsigned* __restrict__ xb2, const unsigned* __restrict__ recs,
                    const int* __restrict__ bcnt, const unsigned short* __restrict__ wb,
                    const float* __restrict__ brel, const float* __restrict__ blin,
                    float* __restrict__ out, float* __restrict__ sums,
                    float* __restrict__ sumsq)
{
    // poolA: acc[64][128] f32 (32 KB); later redS (4 KB)
    // poolB: srec (16 KB) | cnt(1792) | pos(1792) | offs(1796)  = 21764 B;
    //        later smA[64][136] bf16 (17408 B) overlaps srec+cnt (both dead)
    __shared__ __align__(16) char poolA[32768];
    __shared__ __align__(16) char poolB[21768];

    float*    accf = (float*)poolA;
    unsigned* srec = (unsigned*)poolB;
    int*      cnt  = (int*)(poolB + 16384);
    int*      pos  = (int*)(poolB + 18176);
    int*      offs = (int*)(poolB + 19968);      // NKEY+1 ints

    const int bin = blockIdx.x;
    const int tid = threadIdx.x;          // 0..511
    const int l = tid & 63, w = tid >> 6; // wave 0..7
    const int l15 = l & 15, kg = l >> 4;
    const int g16 = l >> 4, c16 = l & 15; // gather: record slot / row chunk

    for (int k = tid; k < NKEY; k += 512) cnt[k] = 0;
    // zero acc (2048 float4 / 512 threads)
    #pragma unroll
    for (int i = 0; i < 4; ++i)
        *(float4*)&accf[(tid + i * 512) * 4] = make_float4(0.f, 0.f, 0.f, 0.f);
    __syncthreads();

    const int n = bcnt[bin];
    const unsigned* rp = recs + (long)bin * CAPG;

    // A1: histogram by key = tile*64 + localdst
    for (int i = tid; i < n; i += 512) {
        unsigned r = rp[i];
        int key = (int)((r & 0xffffu) >> 13) * 64 + (int)((r >> 16) & 63);
        atomicAdd(&cnt[key], 1);
    }
    __syncthreads();

    // A2: exclusive scan over NKEY counters (wave 0, chunked 64-wide + carry)
    if (w == 0) {
        int carry = 0;
        for (int base = 0; base < NKEY; base += 64) {
            int v = cnt[base + l];
            int inc = v;
            #pragma unroll
            for (int d = 1; d < 64; d <<= 1) {
                int u = __shfl_up(inc, d);
                if (l >= d) inc += u;
            }
            offs[base + l] = carry + inc - v;
            pos[base + l]  = carry + inc - v;
            carry += __shfl(inc, 63);
        }
        if (l == 0) offs[NKEY] = carry;
    }
    __syncthreads();

    // A3: scatter into (tile, dst)-sorted order
    for (int i = tid; i < n; i += 512) {
        unsigned r = rp[i];
        int key = (int)((r & 0xffffu) >> 13) * 64 + (int)((r >> 16) & 63);
        int p = atomicAdd(&pos[key], 1);
        srec[p] = r;
    }
    __syncthreads();

    // A4: tile-phased gather; wave w owns dst d = w + 8*di
    for (int t = 0; t < NTILE; ++t) {
        #pragma unroll
        for (int di = 0; di < 8; ++di) {
            const int d = w + 8 * di;
            const int key = t * 64 + d;
            const int b = offs[key], e = offs[key + 1];
            if (b >= e) continue;
            float c[8];
            #pragma unroll
            for (int k = 0; k < 8; ++k) c[k] = 0.f;

            int i = b;
            for (; i + 4 <= e; i += 4) {
                unsigned r = srec[i + g16];
                uint4 q = *((const uint4*)(xb2 + (r & 0xffffu) * 64) + c16);
                acc8(c, q);
            }
            if (i < e) {
                int idx = i + g16;
                if (idx < e) {
                    unsigned r = srec[idx];
                    uint4 q = *((const uint4*)(xb2 + (r & 0xffffu) * 64) + c16);
                    acc8(c, q);
                }
            }
            // fold the 4 record slots
            #pragma unroll
            for (int k = 0; k < 8; ++k) {
                c[k] += __shfl_xor(c[k], 16);
                c[k] += __shfl_xor(c[k], 32);
            }
            if (l < 16) {           // non-atomic: (d) owned by this wave only
                float* ap = accf + d * 128 + c16 * 8;
                float4 v0 = *(float4*)ap;
                float4 v1 = *(float4*)(ap + 4);
                v0.x += c[0]; v0.y += c[1]; v0.z += c[2]; v0.w += c[3];
                v1.x += c[4]; v1.y += c[5]; v1.z += c[6]; v1.w += c[7];
                *(float4*)ap = v0;
                *(float4*)(ap + 4) = v1;
            }
        }
    }
    __syncthreads();   // acc complete; srec/cnt dead

    // A5: pack acc -> smA bf16 (pitch 136 shorts), overlapping srec region
    unsigned short (*smA)[136] = (unsigned short (*)[136])poolB;
    unsigned* smA32 = (unsigned*)poolB;
    #pragma unroll
    for (int it = 0; it < 8; ++it) {
        int idx = tid + it * 512;          // 64*64 = 4096 uint pairs
        int node = idx >> 6, cu = idx & 63;
        float f0 = accf[node * 128 + cu * 2];
        float f1 = accf[node * 128 + cu * 2 + 1];
        smA32[node * 68 + cu] = packbf(f0, f1);
    }
    __syncthreads();

    // ---- Phase B: MLP (8 waves: m = w&3 M-tile, ch = w>>2 col-half) ----
    const unsigned short* Wrelb  = wb;
    const unsigned short* Wrootb = wb + 16384;
    const unsigned short* Wlinb  = wb + 32768;
    const unsigned short* xbs = (const unsigned short*)xb2;

    const int m  = w & 3;
    const int ch = w >> 2;
    const int row = m * 16 + l15;
    const int gA = bin * 64 + row;
    const long gAc = min(gA, NNODES - 1);

    f32x4 acc[4];
    #pragma unroll
    for (int nt = 0; nt < 4; ++nt) acc[nt] = (f32x4){0.f, 0.f, 0.f, 0.f};

    #pragma unroll
    for (int s = 0; s < 8; ++s) {
        const int ko = (s & 3) * 32 + kg * 8;
        bf16x8 a;
        if (s < 4) a = *(const bf16x8*)&smA[row][ko];
        else       a = *(const bf16x8*)(xbs + gAc * 128 + ko);
        const unsigned short* Bb = (s < 4) ? Wrelb : Wrootb;
        #pragma unroll
        for (int nt = 0; nt < 4; ++nt) {
            bf16x8 b = *(const bf16x8*)(Bb + (ch * 64 + nt * 16 + l15) * 128 + ko);
            acc[nt] = __builtin_amdgcn_mfma_f32_16x16x32_bf16(a, b, acc[nt], 0, 0, 0);
        }
    }
    __syncthreads();   // stage-1 smA reads done before cross-wave x2 writes

    #pragma unroll
    for (int nt = 0; nt < 4; ++nt) {
        const int col = ch * 64 + nt * 16 + l15;
        const float br = brel[col];
        #pragma unroll
        for (int r = 0; r < 4; ++r) {
            smA[m * 16 + kg * 4 + r][col] =
                (unsigned short)f2bf(lrelu(acc[nt][r] + br));
        }
    }
    __syncthreads();

    f32x4 acc2[4];
    #pragma unroll
    for (int nt = 0; nt < 4; ++nt) acc2[nt] = (f32x4){0.f, 0.f, 0.f, 0.f};

    #pragma unroll
    for (int s = 0; s < 4; ++s) {
        const int ko = s * 32 + kg * 8;
        bf16x8 a = *(const bf16x8*)&smA[row][ko];
        #pragma unroll
        for (int nt = 0; nt < 4; ++nt) {
            bf16x8 b = *(const bf16x8*)(Wlinb + (ch * 64 + nt * 16 + l15) * 128 + ko);
            acc2[nt] = __builtin_amdgcn_mfma_f32_16x16x32_bf16(a, b, acc2[nt], 0, 0, 0);
        }
    }

    // epilogue: +blin, store fp32, BN partials (redS over acc region, now dead)
    float* redS = (float*)poolA;   // [2 kinds][4 m][128 cols] = 4 KB
    #pragma unroll
    for (int nt = 0; nt < 4; ++nt) {
        const int col = ch * 64 + nt * 16 + l15;
        const float bl = blin[col];
        float ps = 0.f, pq = 0.f;
        #pragma unroll
        for (int r = 0; r < 4; ++r) {
            int g = bin * 64 + m * 16 + kg * 4 + r;
            if (g < NNODES) {
                float y = acc2[nt][r] + bl;
                out[(long)g * 128 + col] = y;
                ps += y; pq += y * y;
            }
        }
        ps += __shfl_xor(ps, 16); ps += __shfl_xor(ps, 32);
        pq += __shfl_xor(pq, 16); pq += __shfl_xor(pq, 32);
        if (kg == 0) {
            redS[(0 * 4 + m) * 128 + col] = ps;
            redS[(1 * 4 + m) * 128 + col] = pq;
        }
    }
    __syncthreads();
    if (tid < 128) {
        float s = redS[0 * 128 + tid] + redS[1 * 128 + tid]
                + redS[2 * 128 + tid] + redS[3 * 128 + tid];
        float q = redS[4 * 128 + tid] + redS[5 * 128 + tid]
                + redS[6 * 128 + tid] + redS[7 * 128 + tid];
        atomicAdd(&sums[tid], s);
        atomicAdd(&sumsq[tid], q);
    }
}

// ---------------- 3. BN finalize ----------------
__global__ void bn_final_kernel(const float* __restrict__ sums, const float* __restrict__ sumsq,
                                const float* __restrict__ gamma, const float* __restrict__ beta,
                                float* __restrict__ ss)
{
    int h = threadIdx.x;
    float mean = sums[h] * (1.f / NNODES);
    float var = sumsq[h] * (1.f / NNODES) - mean * mean;
    float sc = gamma[h] * rsqrtf(var + BN_EPS);
    ss[h] = sc;
    ss[128 + h] = beta[h] - mean * sc;
}

// ---------------- 4. BN apply + leaky (in-place fp32) ----------------
__global__ __launch_bounds__(256)
void bn_apply_kernel(float* __restrict__ out, const float* __restrict__ ss)
{
    __shared__ float s_sc[128], s_sh[128];
    if (threadIdx.x < 128) {
        s_sc[threadIdx.x] = ss[threadIdx.x];
        s_sh[threadIdx.x] = ss[128 + threadIdx.x];
    }
    __syncthreads();
    const int total = NNODES * 32;
    float4* o4 = (float4*)out;
    for (int i = blockIdx.x * 256 + threadIdx.x; i < total; i += gridDim.x * 256) {
        float4 v = o4[i];
        int h = (i & 31) * 4;
        v.x = lrelu(v.x * s_sc[h + 0] + s_sh[h + 0]);
        v.y = lrelu(v.y * s_sc[h + 1] + s_sh[h + 1]);
        v.z = lrelu(v.z * s_sc[h + 2] + s_sh[h + 2]);
        v.w = lrelu(v.w * s_sc[h + 3] + s_sh[h + 3]);
        o4[i] = v;
    }
}

extern "C" void kernel_launch(void* const* d_in, const int* in_sizes, int n_in,
                              void* d_out, int out_size, void* d_ws, size_t ws_size,
                              hipStream_t stream)
{
    const float* x     = (const float*)d_in[0];
    const int*   ei    = (const int*)d_in[1];
    const float* Wrel  = (const float*)d_in[3];
    const float* brel  = (const float*)d_in[4];
    const float* Wroot = (const float*)d_in[5];
    const float* Wlin  = (const float*)d_in[6];
    const float* blin  = (const float*)d_in[7];
    const float* gamma = (const float*)d_in[8];
    const float* beta  = (const float*)d_in[9];
    float* out = (float*)d_out;

    const int n_edges = in_sizes[1] / 2;
    const int* src = ei;
    const int* dst = ei + n_edges;

    // workspace layout (bytes):
    // xb    @ 0          : 12,800,000   (x as bf16)
    // recs  @ 12,800,000 : 12,812,288   (NBINS*CAPG*4)
    // wb    @ 25,612,288 : 98,304
    // bcnt  @ 25,710,592 : 3,128        } memset together (5,248 B)
    // stats @ 25,713,792 : 2,048        }   -> total 25.72 MB
    char* ws = (char*)d_ws;
    unsigned short* xb   = (unsigned short*)ws;
    unsigned*       recs = (unsigned*)(ws + 12800000);
    unsigned short* wb   = (unsigned short*)(ws + 25612288);
    int*   bcnt  = (int*)(ws + 25710592);
    float* sums  = (float*)(ws + 25713792);
    float* sumsq = sums + 128;
    float* ss    = sums + 256;

    hipMemsetAsync(bcnt, 0, 5248, stream);   // bcnt + stats

    prep_kernel<<<4096, 256, 0, stream>>>(x, Wrel, Wroot, Wlin, (unsigned*)xb, (unsigned*)wb);
    bin_kernel<<<PH1B, 256, 0, stream>>>(src, dst, bcnt, recs, n_edges);
    agg_mlp_kernel<<<NBINS, 512, 0, stream>>>((const unsigned*)xb, recs, bcnt, wb,
                                              brel, blin, out, sums, sumsq);
    bn_final_kernel<<<1, 128, 0, stream>>>(sums, sumsq, gamma, beta, ss);
    bn_apply_kernel<<<2048, 256, 0, stream>>>(out, ss);
}

// Round 12
// 195.313 us; speedup vs baseline: 1.2024x; 1.2024x over previous
//
#include <hip/hip_runtime.h>

#define NNODES 50000
#define NEG 0.01f
#define BN_EPS 1e-5f

#define BINSZ 64             // dst nodes per bin
#define NBINS 782            // ceil(50000/64)
#define CAPG 4096            // record capacity per bin (mean ~2046)
#define PH1B 256             // phase-1 blocks (1 per CU)
#define RING 32              // ring slots per bin (flush granule 16)

typedef __attribute__((ext_vector_type(8))) short bf16x8;
typedef __attribute__((ext_vector_type(4))) float f32x4;

__device__ __forceinline__ float lrelu(float v) { return v >= 0.f ? v : NEG * v; }
__device__ __forceinline__ float bf_lo(unsigned u) { return __uint_as_float(u << 16); }
__device__ __forceinline__ float bf_hi(unsigned u) { return __uint_as_float(u & 0xffff0000u); }
__device__ __forceinline__ unsigned f2bf(float x) {          // RNE
    unsigned u = __float_as_uint(x);
    return (u + 0x7fffu + ((u >> 16) & 1u)) >> 16;
}
__device__ __forceinline__ unsigned packbf(float lo, float hi) {
    unsigned b = __float_as_uint(hi);
    b = (b + 0x7fffu + ((b >> 16) & 1u)) & 0xffff0000u;
    return (f2bf(lo) & 0xffffu) | b;
}
__device__ __forceinline__ void acc8(float* c, uint4 q) {
    c[0] += bf_lo(q.x); c[1] += bf_hi(q.x);
    c[2] += bf_lo(q.y); c[3] += bf_hi(q.y);
    c[4] += bf_lo(q.z); c[5] += bf_hi(q.z);
    c[6] += bf_lo(q.w); c[7] += bf_hi(q.w);
}

// ---------------- 0. convert x + weights to bf16 ----------------
__global__ __launch_bounds__(256)
void prep_kernel(const float* __restrict__ x, const float* __restrict__ Wrel,
                 const float* __restrict__ Wroot, const float* __restrict__ Wlin,
                 unsigned* __restrict__ xb2, unsigned* __restrict__ wb2)
{
    const int NPX = 3200000;           // float pairs in x
    const int NPW = 24576;             // float pairs in 3 weight mats
    for (int i = blockIdx.x * 256 + threadIdx.x; i < NPX + NPW; i += gridDim.x * 256) {
        if (i < NPX) {
            float2 v = ((const float2*)x)[i];
            xb2[i] = packbf(v.x, v.y);
        } else {
            int j = i - NPX;
            const float* W = (j < 8192) ? Wrel : (j < 16384 ? Wroot : Wlin);
            float2 v = ((const float2*)W)[j & 8191];
            wb2[j] = packbf(v.x, v.y);
        }
    }
}

// ---------------- 1. multisplit: bin edges by dst>>6, line-combined flushes ----------------
__global__ __launch_bounds__(256)
void bin_kernel(const int* __restrict__ src, const int* __restrict__ dst,
                int* __restrict__ bcnt, unsigned* __restrict__ recs, int n_edges)
{
    __shared__ __align__(16) unsigned buf[NBINS][RING];   // 100 KB (grid=1/CU: free)
    __shared__ int cnt[NBINS];
    __shared__ int flushed[NBINS];

    const int tid = threadIdx.x;
    for (int t = tid; t < NBINS; t += 256) { cnt[t] = 0; flushed[t] = 0; }
    __syncthreads();

    const int per = (n_edges + PH1B - 1) / PH1B;
    const int begin = blockIdx.x * per;
    const int end = min(begin + per, n_edges);

    for (int base = begin; base < end; base += 256) {
        int i = base + tid;
        if (i < end) {
            int s = src[i], d = dst[i];
            int b = d >> 6;
            unsigned rec = (unsigned)s | ((unsigned)(d & 63) << 16);
            int pos = atomicAdd(&cnt[b], 1);
            buf[b][pos & (RING - 1)] = rec;
        }
        __syncthreads();
        for (int t = tid; t < NBINS; t += 256) {
            int c = cnt[t];
            int f = flushed[t];
            while (c - f >= 16) {                    // 16 recs = 64B = 1 line
                int gbase = atomicAdd(&bcnt[t], 16);
                unsigned* dp = recs + (long)t * CAPG + gbase;
                int ro = f & (RING - 1);             // multiple of 16, no wrap
                #pragma unroll
                for (int k = 0; k < 4; ++k)
                    *(uint4*)(dp + k * 4) = *(uint4*)&buf[t][ro + k * 4];
                f += 16;
            }
            flushed[t] = f;
        }
        __syncthreads();
    }
    for (int t = tid; t < NBINS; t += 256) {
        int c = cnt[t], f = flushed[t];
        int n = c - f;
        if (n > 0) {
            int gbase = atomicAdd(&bcnt[t], n);
            unsigned* dp = recs + (long)t * CAPG + gbase;
            int ro = f & (RING - 1);
            for (int k = 0; k < n; ++k) dp[k] = buf[t][ro + k];
        }
    }
}

// ---------------- 2. FUSED per-bin aggregate (channel-quartered) + MLP + BN ----------------
// Sort by dst only (64 keys, long runs ~32). Gather sweeps the 128 channels in
// 4 quarter-sweeps of 64 B/record; hot xb footprint per sweep = 3.2 MB -> L2
// resident per XCD; grid 782 fully co-resident (4 blocks/CU) so all blocks
// sweep quarters near-lockstep. Per batch: 16 records via ONE uint4 load/lane
// (slot g4 = l>>2, chunk c4 = l&3). Per (dst,quarter): fold xor(4,8,16,32),
// lanes 0-3 pack bf16 direct to smA. No LDS fp32 acc, no cross-tile state.
__global__ __launch_bounds__(512, 4)
void agg_mlp_kernel(const unsigned* __restrict__ xb2, const unsigned* __restrict__ recs,
                    const int* __restrict__ bcnt, const unsigned short* __restrict__ wb,
                    const float* __restrict__ brel, const float* __restrict__ blin,
                    float* __restrict__ out, float* __restrict__ sums,
                    float* __restrict__ sumsq)
{
    __shared__ unsigned srec[CAPG];                       // 16 KB (later: BN scratch)
    __shared__ int cnt[BINSZ];
    __shared__ int pos[BINSZ];
    __shared__ int offs[BINSZ + 1];
    __shared__ __align__(16) unsigned short smA[BINSZ][136];  // 17.4 KB

    const int bin = blockIdx.x;
    const int tid = threadIdx.x;          // 0..511
    const int l = tid & 63, w = tid >> 6; // wave 0..7
    const int l15 = l & 15, kg = l >> 4;
    const int g4 = l >> 2, c4 = l & 3;    // gather: record slot / 16B chunk

    if (tid < BINSZ) cnt[tid] = 0;
    __syncthreads();

    const int n = bcnt[bin];
    const unsigned* rp = recs + (long)bin * CAPG;

    // A1: histogram by local dst
    for (int i = tid; i < n; i += 512)
        atomicAdd(&cnt[(rp[i] >> 16) & 63], 1);
    __syncthreads();

    // A2: exclusive scan over 64 counters (wave 0)
    if (tid < 64) {
        int v = cnt[tid];
        int inc = v;
        #pragma unroll
        for (int d = 1; d < 64; d <<= 1) {
            int u = __shfl_up(inc, d);
            if (tid >= d) inc += u;
        }
        offs[tid] = inc - v;
        pos[tid] = inc - v;
        if (tid == 63) offs[64] = inc;
    }
    __syncthreads();

    // A3: scatter into dst-sorted order
    for (int i = tid; i < n; i += 512) {
        unsigned r = rp[i];
        int p = atomicAdd(&pos[(r >> 16) & 63], 1);
        srec[p] = r;
    }
    __syncthreads();

    // A4: channel-quartered gather; wave w owns dst d = w + 8*di
    unsigned* smA32 = (unsigned*)smA;
    for (int q = 0; q < 4; ++q) {
        #pragma unroll
        for (int di = 0; di < 8; ++di) {
            const int d = w + 8 * di;
            const int b = offs[d], e = offs[d + 1];
            float c[8];
            #pragma unroll
            for (int k = 0; k < 8; ++k) c[k] = 0.f;

            for (int i = b; i < e; i += 16) {       // 16 records per batch
                int idx = i + g4;
                if (idx < e) {
                    unsigned r = srec[idx];
                    uint4 qv = *((const uint4*)(xb2 + (r & 0xffffu) * 64 + q * 16) + c4);
                    acc8(c, qv);
                }
            }
            // fold the 16 record slots (lane bits 2..5)
            #pragma unroll
            for (int k = 0; k < 8; ++k) {
                c[k] += __shfl_xor(c[k], 4);
                c[k] += __shfl_xor(c[k], 8);
                c[k] += __shfl_xor(c[k], 16);
                c[k] += __shfl_xor(c[k], 32);
            }
            if (l < 4) {
                uint4 o;
                o.x = packbf(c[0], c[1]); o.y = packbf(c[2], c[3]);
                o.z = packbf(c[4], c[5]); o.w = packbf(c[6], c[7]);
                *((uint4*)(smA32 + d * 68 + q * 16) + c4) = o;
            }
        }
    }
    __syncthreads();   // smA ready; srec reads complete (free for reuse)

    // ---- Phase B: MLP (8 waves: m = w&3 M-tile, ch = w>>2 col-half) ----
    const unsigned short* Wrelb  = wb;
    const unsigned short* Wrootb = wb + 16384;
    const unsigned short* Wlinb  = wb + 32768;
    const unsigned short* xbs = (const unsigned short*)xb2;

    const int m  = w & 3;
    const int ch = w >> 2;
    const int row = m * 16 + l15;
    const int gA = bin * 64 + row;
    const long gAc = min(gA, NNODES - 1);

    f32x4 acc[4];
    #pragma unroll
    for (int nt = 0; nt < 4; ++nt) acc[nt] = (f32x4){0.f, 0.f, 0.f, 0.f};

    #pragma unroll
    for (int s = 0; s < 8; ++s) {
        const int ko = (s & 3) * 32 + kg * 8;
        bf16x8 a;
        if (s < 4) a = *(const bf16x8*)&smA[row][ko];
        else       a = *(const bf16x8*)(xbs + gAc * 128 + ko);
        const unsigned short* Bb = (s < 4) ? Wrelb : Wrootb;
        #pragma unroll
        for (int nt = 0; nt < 4; ++nt) {
            bf16x8 b = *(const bf16x8*)(Bb + (ch * 64 + nt * 16 + l15) * 128 + ko);
            acc[nt] = __builtin_amdgcn_mfma_f32_16x16x32_bf16(a, b, acc[nt], 0, 0, 0);
        }
    }
    __syncthreads();   // stage-1 smA reads done before cross-wave x2 writes

    #pragma unroll
    for (int nt = 0; nt < 4; ++nt) {
        const int col = ch * 64 + nt * 16 + l15;
        const float br = brel[col];
        #pragma unroll
        for (int r = 0; r < 4; ++r) {
            smA[m * 16 + kg * 4 + r][col] =
                (unsigned short)f2bf(lrelu(acc[nt][r] + br));
        }
    }
    __syncthreads();

    f32x4 acc2[4];
    #pragma unroll
    for (int nt = 0; nt < 4; ++nt) acc2[nt] = (f32x4){0.f, 0.f, 0.f, 0.f};

    #pragma unroll
    for (int s = 0; s < 4; ++s) {
        const int ko = s * 32 + kg * 8;
        bf16x8 a = *(const bf16x8*)&smA[row][ko];
        #pragma unroll
        for (int nt = 0; nt < 4; ++nt) {
            bf16x8 b = *(const bf16x8*)(Wlinb + (ch * 64 + nt * 16 + l15) * 128 + ko);
            acc2[nt] = __builtin_amdgcn_mfma_f32_16x16x32_bf16(a, b, acc2[nt], 0, 0, 0);
        }
    }

    // epilogue: +blin, store fp32, BN partials via LDS (srec as scratch)
    float* redS = (float*)srec;   // [2 kinds][4 m][128 cols] = 4 KB
    #pragma unroll
    for (int nt = 0; nt < 4; ++nt) {
        const int col = ch * 64 + nt * 16 + l15;
        const float bl = blin[col];
        float ps = 0.f, pq = 0.f;
        #pragma unroll
        for (int r = 0; r < 4; ++r) {
            int g = bin * 64 + m * 16 + kg * 4 + r;
            if (g < NNODES) {
                float y = acc2[nt][r] + bl;
                out[(long)g * 128 + col] = y;
                ps += y; pq += y * y;
            }
        }
        ps += __shfl_xor(ps, 16); ps += __shfl_xor(ps, 32);
        pq += __shfl_xor(pq, 16); pq += __shfl_xor(pq, 32);
        if (kg == 0) {
            redS[(0 * 4 + m) * 128 + col] = ps;
            redS[(1 * 4 + m) * 128 + col] = pq;
        }
    }
    __syncthreads();
    if (tid < 128) {
        float s = redS[0 * 128 + tid] + redS[1 * 128 + tid]
                + redS[2 * 128 + tid] + redS[3 * 128 + tid];
        float q = redS[4 * 128 + tid] + redS[5 * 128 + tid]
                + redS[6 * 128 + tid] + redS[7 * 128 + tid];
        atomicAdd(&sums[tid], s);
        atomicAdd(&sumsq[tid], q);
    }
}

// ---------------- 3. BN finalize ----------------
__global__ void bn_final_kernel(const float* __restrict__ sums, const float* __restrict__ sumsq,
                                const float* __restrict__ gamma, const float* __restrict__ beta,
                                float* __restrict__ ss)
{
    int h = threadIdx.x;
    float mean = sums[h] * (1.f / NNODES);
    float var = sumsq[h] * (1.f / NNODES) - mean * mean;
    float sc = gamma[h] * rsqrtf(var + BN_EPS);
    ss[h] = sc;
    ss[128 + h] = beta[h] - mean * sc;
}

// ---------------- 4. BN apply + leaky (in-place fp32) ----------------
__global__ __launch_bounds__(256)
void bn_apply_kernel(float* __restrict__ out, const float* __restrict__ ss)
{
    __shared__ float s_sc[128], s_sh[128];
    if (threadIdx.x < 128) {
        s_sc[threadIdx.x] = ss[threadIdx.x];
        s_sh[threadIdx.x] = ss[128 + threadIdx.x];
    }
    __syncthreads();
    const int total = NNODES * 32;
    float4* o4 = (float4*)out;
    for (int i = blockIdx.x * 256 + threadIdx.x; i < total; i += gridDim.x * 256) {
        float4 v = o4[i];
        int h = (i & 31) * 4;
        v.x = lrelu(v.x * s_sc[h + 0] + s_sh[h + 0]);
        v.y = lrelu(v.y * s_sc[h + 1] + s_sh[h + 1]);
        v.z = lrelu(v.z * s_sc[h + 2] + s_sh[h + 2]);
        v.w = lrelu(v.w * s_sc[h + 3] + s_sh[h + 3]);
        o4[i] = v;
    }
}

extern "C" void kernel_launch(void* const* d_in, const int* in_sizes, int n_in,
                              void* d_out, int out_size, void* d_ws, size_t ws_size,
                              hipStream_t stream)
{
    const float* x     = (const float*)d_in[0];
    const int*   ei    = (const int*)d_in[1];
    const float* Wrel  = (const float*)d_in[3];
    const float* brel  = (const float*)d_in[4];
    const float* Wroot = (const float*)d_in[5];
    const float* Wlin  = (const float*)d_in[6];
    const float* blin  = (const float*)d_in[7];
    const float* gamma = (const float*)d_in[8];
    const float* beta  = (const float*)d_in[9];
    float* out = (float*)d_out;

    const int n_edges = in_sizes[1] / 2;
    const int* src = ei;
    const int* dst = ei + n_edges;

    // workspace layout (bytes):
    // xb    @ 0          : 12,800,000   (x as bf16)
    // recs  @ 12,800,000 : 12,812,288   (NBINS*CAPG*4)
    // wb    @ 25,612,288 : 98,304
    // bcnt  @ 25,710,592 : 3,128        } memset together (5,248 B)
    // stats @ 25,713,792 : 2,048        }   -> total 25.72 MB
    char* ws = (char*)d_ws;
    unsigned short* xb   = (unsigned short*)ws;
    unsigned*       recs = (unsigned*)(ws + 12800000);
    unsigned short* wb   = (unsigned short*)(ws + 25612288);
    int*   bcnt  = (int*)(ws + 25710592);
    float* sums  = (float*)(ws + 25713792);
    float* sumsq = sums + 128;
    float* ss    = sums + 256;

    hipMemsetAsync(bcnt, 0, 5248, stream);   // bcnt + stats

    prep_kernel<<<4096, 256, 0, stream>>>(x, Wrel, Wroot, Wlin, (unsigned*)xb, (unsigned*)wb);
    bin_kernel<<<PH1B, 256, 0, stream>>>(src, dst, bcnt, recs, n_edges);
    agg_mlp_kernel<<<NBINS, 512, 0, stream>>>((const unsigned*)xb, recs, bcnt, wb,
                                              brel, blin, out, sums, sumsq);
    bn_final_kernel<<<1, 128, 0, stream>>>(sums, sumsq, gamma, beta, ss);
    bn_apply_kernel<<<2048, 256, 0, stream>>>(out, ss);
}

// Round 13
// 175.772 us; speedup vs baseline: 1.3361x; 1.1112x over previous
//
#include <hip/hip_runtime.h>

#define NNODES 50000
#define NEG 0.01f
#define BN_EPS 1e-5f

#define BINSZ 64             // dst nodes per bin
#define NBINS 782            // ceil(50000/64)
#define CAPG 4096            // record capacity per bin (mean ~2046)
#define PH1B 256             // phase-1 blocks (1 per CU)
#define RING 32              // ring slots per bin (flush granule 16; 16-slot slack)

typedef __attribute__((ext_vector_type(8))) short bf16x8;
typedef __attribute__((ext_vector_type(4))) float f32x4;

__device__ __forceinline__ float lrelu(float v) { return v >= 0.f ? v : NEG * v; }
__device__ __forceinline__ float bf_lo(unsigned u) { return __uint_as_float(u << 16); }
__device__ __forceinline__ float bf_hi(unsigned u) { return __uint_as_float(u & 0xffff0000u); }
__device__ __forceinline__ unsigned f2bf(float x) {          // RNE
    unsigned u = __float_as_uint(x);
    return (u + 0x7fffu + ((u >> 16) & 1u)) >> 16;
}
__device__ __forceinline__ unsigned packbf(float lo, float hi) {
    unsigned b = __float_as_uint(hi);
    b = (b + 0x7fffu + ((b >> 16) & 1u)) & 0xffff0000u;
    return (f2bf(lo) & 0xffffu) | b;
}
__device__ __forceinline__ void acc8(float* c, uint4 q) {
    c[0] += bf_lo(q.x); c[1] += bf_hi(q.x);
    c[2] += bf_lo(q.y); c[3] += bf_hi(q.y);
    c[4] += bf_lo(q.z); c[5] += bf_hi(q.z);
    c[6] += bf_lo(q.w); c[7] += bf_hi(q.w);
}

// ---------------- 0. convert x + weights to bf16 ----------------
__global__ __launch_bounds__(256)
void prep_kernel(const float* __restrict__ x, const float* __restrict__ Wrel,
                 const float* __restrict__ Wroot, const float* __restrict__ Wlin,
                 unsigned* __restrict__ xb2, unsigned* __restrict__ wb2)
{
    const int NPX = 3200000;           // float pairs in x
    const int NPW = 24576;             // float pairs in 3 weight mats
    for (int i = blockIdx.x * 256 + threadIdx.x; i < NPX + NPW; i += gridDim.x * 256) {
        if (i < NPX) {
            float2 v = ((const float2*)x)[i];
            xb2[i] = packbf(v.x, v.y);
        } else {
            int j = i - NPX;
            const float* W = (j < 8192) ? Wrel : (j < 16384 ? Wroot : Wlin);
            float2 v = ((const float2*)W)[j & 8191];
            wb2[j] = packbf(v.x, v.y);
        }
    }
}

// ---------------- 1. multisplit: bin edges by dst>>6, line-combined flushes ----------------
__global__ __launch_bounds__(256)
void bin_kernel(const int* __restrict__ src, const int* __restrict__ dst,
                int* __restrict__ bcnt, unsigned* __restrict__ recs, int n_edges)
{
    __shared__ __align__(16) unsigned buf[NBINS][RING];   // 100 KB (grid=1/CU: free)
    __shared__ int cnt[NBINS];
    __shared__ int flushed[NBINS];

    const int tid = threadIdx.x;
    for (int t = tid; t < NBINS; t += 256) { cnt[t] = 0; flushed[t] = 0; }
    __syncthreads();

    const int per = (n_edges + PH1B - 1) / PH1B;
    const int begin = blockIdx.x * per;
    const int end = min(begin + per, n_edges);

    for (int base = begin; base < end; base += 256) {
        int i = base + tid;
        if (i < end) {
            int s = src[i], d = dst[i];
            int b = d >> 6;
            unsigned rec = (unsigned)s | ((unsigned)(d & 63) << 16);
            int pos = atomicAdd(&cnt[b], 1);
            buf[b][pos & (RING - 1)] = rec;
        }
        __syncthreads();
        for (int t = tid; t < NBINS; t += 256) {
            int c = cnt[t];
            int f = flushed[t];
            while (c - f >= 16) {                    // 16 recs = 64B = 1 line
                int gbase = atomicAdd(&bcnt[t], 16);
                unsigned* dp = recs + (long)t * CAPG + gbase;
                int ro = f & (RING - 1);             // multiple of 16, no wrap
                #pragma unroll
                for (int k = 0; k < 4; ++k)
                    *(uint4*)(dp + k * 4) = *(uint4*)&buf[t][ro + k * 4];
                f += 16;
            }
            flushed[t] = f;
        }
        __syncthreads();
    }
    for (int t = tid; t < NBINS; t += 256) {
        int c = cnt[t], f = flushed[t];
        int n = c - f;
        if (n > 0) {
            int gbase = atomicAdd(&bcnt[t], n);
            unsigned* dp = recs + (long)t * CAPG + gbase;
            int ro = f & (RING - 1);
            for (int k = 0; k < n; ++k) dp[k] = buf[t][ro + k];
        }
    }
}

// ---------------- 2. FUSED per-bin aggregate + MLP + BN (R10 structure) ----------------
// x3 output written as bf16 pairs into this bin's own recs region (dead after
// A3): x3b uint index = bin*4096 + local*64 + c == (global node)*64 + c, i.e.
// a clean linear [50048][64]-uint array. Halves agg WRITE and bn_apply READ.
__global__ __launch_bounds__(512, 6)
void agg_mlp_kernel(const unsigned* __restrict__ xb2, const unsigned* __restrict__ recs,
                    unsigned* __restrict__ x3b,
                    const int* __restrict__ bcnt, const unsigned short* __restrict__ wb,
                    const float* __restrict__ brel, const float* __restrict__ blin,
                    float* __restrict__ sums, float* __restrict__ sumsq)
{
    __shared__ unsigned srec[CAPG];                       // 16 KB (later: BN scratch)
    __shared__ int cnt[BINSZ];
    __shared__ int pos[BINSZ];
    __shared__ int offs[BINSZ + 1];
    __shared__ __align__(16) unsigned short smA[BINSZ][136];  // 17.4 KB

    const int bin = blockIdx.x;
    const int tid = threadIdx.x;          // 0..511
    const int l = tid & 63, w = tid >> 6; // wave 0..7
    const int l15 = l & 15, kg = l >> 4;
    const int g16 = l >> 4, c16 = l & 15; // gather: record slot / row chunk

    if (tid < BINSZ) cnt[tid] = 0;
    __syncthreads();

    const int n = bcnt[bin];
    const unsigned* rp = recs + (long)bin * CAPG;

    // A1: histogram by local dst
    for (int i = tid; i < n; i += 512)
        atomicAdd(&cnt[(rp[i] >> 16) & 63], 1);
    __syncthreads();

    // A2: exclusive scan over 64 counters (wave 0)
    if (tid < 64) {
        int v = cnt[tid];
        int inc = v;
        #pragma unroll
        for (int d = 1; d < 64; d <<= 1) {
            int u = __shfl_up(inc, d);
            if (tid >= d) inc += u;
        }
        offs[tid] = inc - v;
        pos[tid] = inc - v;
        if (tid == 63) offs[64] = inc;
    }
    __syncthreads();

    // A3: scatter into dst-sorted order
    for (int i = tid; i < n; i += 512) {
        unsigned r = rp[i];
        int p = atomicAdd(&pos[(r >> 16) & 63], 1);
        srec[p] = r;
    }
    __syncthreads();   // rp fully consumed -> this bin's recs region reusable

    // A4: per-node register accumulation, uint4 gather (4 records/load)
    unsigned* smA32 = (unsigned*)smA;
    for (int lo = w; lo < BINSZ; lo += 8) {
        const int b = offs[lo], e = offs[lo + 1];
        float c[8];
        #pragma unroll
        for (int k = 0; k < 8; ++k) c[k] = 0.f;

        int i = b;
        for (; i + 16 <= e; i += 16) {
            unsigned r0 = srec[i + g16];
            unsigned r1 = srec[i + 4 + g16];
            unsigned r2 = srec[i + 8 + g16];
            unsigned r3 = srec[i + 12 + g16];
            uint4 q0 = *((const uint4*)(xb2 + (r0 & 0xffffu) * 64) + c16);
            uint4 q1 = *((const uint4*)(xb2 + (r1 & 0xffffu) * 64) + c16);
            uint4 q2 = *((const uint4*)(xb2 + (r2 & 0xffffu) * 64) + c16);
            uint4 q3 = *((const uint4*)(xb2 + (r3 & 0xffffu) * 64) + c16);
            acc8(c, q0); acc8(c, q1); acc8(c, q2); acc8(c, q3);
        }
        for (; i + 4 <= e; i += 4) {
            unsigned r = srec[i + g16];
            uint4 q = *((const uint4*)(xb2 + (r & 0xffffu) * 64) + c16);
            acc8(c, q);
        }
        if (i < e) {                                   // 1..3 leftover records
            int idx = i + g16;
            if (idx < e) {
                unsigned r = srec[idx];
                uint4 q = *((const uint4*)(xb2 + (r & 0xffffu) * 64) + c16);
                acc8(c, q);
            }
        }
        // fold the 4 record slots
        #pragma unroll
        for (int k = 0; k < 8; ++k) {
            c[k] += __shfl_xor(c[k], 16);
            c[k] += __shfl_xor(c[k], 32);
        }
        if (l < 16) {
            uint4 o;
            o.x = packbf(c[0], c[1]); o.y = packbf(c[2], c[3]);
            o.z = packbf(c[4], c[5]); o.w = packbf(c[6], c[7]);
            *((uint4*)(smA32 + lo * 68) + c16) = o;
        }
    }
    __syncthreads();   // smA ready; srec free for reuse

    // ---- Phase B: MLP (8 waves: m = w&3 M-tile, ch = w>>2 col-half) ----
    const unsigned short* Wrelb  = wb;
    const unsigned short* Wrootb = wb + 16384;
    const unsigned short* Wlinb  = wb + 32768;
    const unsigned short* xbs = (const unsigned short*)xb2;

    const int m  = w & 3;
    const int ch = w >> 2;
    const int row = m * 16 + l15;
    const int gA = bin * 64 + row;
    const long gAc = min(gA, NNODES - 1);

    f32x4 acc[4];
    #pragma unroll
    for (int nt = 0; nt < 4; ++nt) acc[nt] = (f32x4){0.f, 0.f, 0.f, 0.f};

    #pragma unroll
    for (int s = 0; s < 8; ++s) {
        const int ko = (s & 3) * 32 + kg * 8;
        bf16x8 a;
        if (s < 4) a = *(const bf16x8*)&smA[row][ko];
        else       a = *(const bf16x8*)(xbs + gAc * 128 + ko);
        const unsigned short* Bb = (s < 4) ? Wrelb : Wrootb;
        #pragma unroll
        for (int nt = 0; nt < 4; ++nt) {
            bf16x8 b = *(const bf16x8*)(Bb + (ch * 64 + nt * 16 + l15) * 128 + ko);
            acc[nt] = __builtin_amdgcn_mfma_f32_16x16x32_bf16(a, b, acc[nt], 0, 0, 0);
        }
    }
    __syncthreads();   // stage-1 smA reads done before cross-wave x2 writes

    #pragma unroll
    for (int nt = 0; nt < 4; ++nt) {
        const int col = ch * 64 + nt * 16 + l15;
        const float br = brel[col];
        #pragma unroll
        for (int r = 0; r < 4; ++r) {
            smA[m * 16 + kg * 4 + r][col] =
                (unsigned short)f2bf(lrelu(acc[nt][r] + br));
        }
    }
    __syncthreads();

    f32x4 acc2[4];
    #pragma unroll
    for (int nt = 0; nt < 4; ++nt) acc2[nt] = (f32x4){0.f, 0.f, 0.f, 0.f};

    #pragma unroll
    for (int s = 0; s < 4; ++s) {
        const int ko = s * 32 + kg * 8;
        bf16x8 a = *(const bf16x8*)&smA[row][ko];
        #pragma unroll
        for (int nt = 0; nt < 4; ++nt) {
            bf16x8 b = *(const bf16x8*)(Wlinb + (ch * 64 + nt * 16 + l15) * 128 + ko);
            acc2[nt] = __builtin_amdgcn_mfma_f32_16x16x32_bf16(a, b, acc2[nt], 0, 0, 0);
        }
    }

    // epilogue: +blin, BN partials (fp32, exact), x3 -> bf16 pairs into recs alias
    unsigned* x3o = x3b + (long)bin * CAPG;   // == global [node][64] uints
    float* redS = (float*)srec;               // [2 kinds][4 m][128 cols] = 4 KB
    #pragma unroll
    for (int nt = 0; nt < 4; ++nt) {
        const int col = ch * 64 + nt * 16 + l15;
        const float bl = blin[col];
        float ps = 0.f, pq = 0.f;
        #pragma unroll
        for (int r = 0; r < 4; ++r) {
            int lrow = m * 16 + kg * 4 + r;
            int g = bin * 64 + lrow;
            float y = acc2[nt][r] + bl;
            float yy = __shfl_xor(y, 1);      // partner column (col^1), same row
            if (g < NNODES) {
                ps += y; pq += y * y;
                if ((l15 & 1) == 0)
                    x3o[lrow * 64 + (ch * 32 + nt * 8 + (l15 >> 1))] = packbf(y, yy);
            }
        }
        ps += __shfl_xor(ps, 16); ps += __shfl_xor(ps, 32);
        pq += __shfl_xor(pq, 16); pq += __shfl_xor(pq, 32);
        if (kg == 0) {
            redS[(0 * 4 + m) * 128 + col] = ps;
            redS[(1 * 4 + m) * 128 + col] = pq;
        }
    }
    __syncthreads();
    if (tid < 128) {
        float s = redS[0 * 128 + tid] + redS[1 * 128 + tid]
                + redS[2 * 128 + tid] + redS[3 * 128 + tid];
        float q = redS[4 * 128 + tid] + redS[5 * 128 + tid]
                + redS[6 * 128 + tid] + redS[7 * 128 + tid];
        atomicAdd(&sums[tid], s);
        atomicAdd(&sumsq[tid], q);
    }
}

// ---------------- 3. BN finalize + apply + leaky (fused; reads x3 bf16) ----------------
__global__ __launch_bounds__(256)
void bn_apply_kernel(const unsigned* __restrict__ x3b,
                     const float* __restrict__ sums, const float* __restrict__ sumsq,
                     const float* __restrict__ gamma, const float* __restrict__ beta,
                     float* __restrict__ out)
{
    __shared__ float s_sc[128], s_sh[128];
    if (threadIdx.x < 128) {
        int h = threadIdx.x;
        float mean = sums[h] * (1.f / NNODES);
        float var = sumsq[h] * (1.f / NNODES) - mean * mean;
        float sc = gamma[h] * rsqrtf(var + BN_EPS);
        s_sc[h] = sc;
        s_sh[h] = beta[h] - mean * sc;
    }
    __syncthreads();
    const int total = NNODES * 64;        // uint (bf16-pair) count
    float2* o2 = (float2*)out;
    for (int i = blockIdx.x * 256 + threadIdx.x; i < total; i += gridDim.x * 256) {
        unsigned u = x3b[i];
        int h = (i & 63) * 2;
        float2 v;
        v.x = lrelu(bf_lo(u) * s_sc[h + 0] + s_sh[h + 0]);
        v.y = lrelu(bf_hi(u) * s_sc[h + 1] + s_sh[h + 1]);
        o2[i] = v;
    }
}

extern "C" void kernel_launch(void* const* d_in, const int* in_sizes, int n_in,
                              void* d_out, int out_size, void* d_ws, size_t ws_size,
                              hipStream_t stream)
{
    const float* x     = (const float*)d_in[0];
    const int*   ei    = (const int*)d_in[1];
    const float* Wrel  = (const float*)d_in[3];
    const float* brel  = (const float*)d_in[4];
    const float* Wroot = (const float*)d_in[5];
    const float* Wlin  = (const float*)d_in[6];
    const float* blin  = (const float*)d_in[7];
    const float* gamma = (const float*)d_in[8];
    const float* beta  = (const float*)d_in[9];
    float* out = (float*)d_out;

    const int n_edges = in_sizes[1] / 2;
    const int* src = ei;
    const int* dst = ei + n_edges;

    // workspace layout (bytes):
    // xb       @ 0          : 12,800,000   (x as bf16)
    // recs∪x3b @ 12,800,000 : 12,812,288   (NBINS*CAPG*4; x3 bf16 aliases linearly)
    // wb       @ 25,612,288 : 98,304
    // bcnt     @ 25,710,592 : 3,128        } memset together (5,248 B)
    // stats    @ 25,713,792 : 2,048        }   -> total 25.72 MB
    char* ws = (char*)d_ws;
    unsigned short* xb   = (unsigned short*)ws;
    unsigned*       recs = (unsigned*)(ws + 12800000);
    unsigned*       x3b  = (unsigned*)(ws + 12800000);
    unsigned short* wb   = (unsigned short*)(ws + 25612288);
    int*   bcnt  = (int*)(ws + 25710592);
    float* sums  = (float*)(ws + 25713792);
    float* sumsq = sums + 128;

    hipMemsetAsync(bcnt, 0, 5248, stream);   // bcnt + stats

    prep_kernel<<<4096, 256, 0, stream>>>(x, Wrel, Wroot, Wlin, (unsigned*)xb, (unsigned*)wb);
    bin_kernel<<<PH1B, 256, 0, stream>>>(src, dst, bcnt, recs, n_edges);
    agg_mlp_kernel<<<NBINS, 512, 0, stream>>>((const unsigned*)xb, recs, x3b, bcnt, wb,
                                              brel, blin, sums, sumsq);
    bn_apply_kernel<<<2048, 256, 0, stream>>>(x3b, sums, sumsq, gamma, beta, out);
}

// Round 14
// 168.811 us; speedup vs baseline: 1.3912x; 1.0412x over previous
//
#include <hip/hip_runtime.h>

#define NNODES 50000
#define NEG 0.01f
#define BN_EPS 1e-5f

#define BINSZ 64             // dst nodes per bin
#define NBINS 782            // ceil(50000/64)
#define CAPG 4096            // record capacity per bin (mean ~2046)
#define PH1B 256             // phase-1 blocks (1 per CU)
#define RING 32              // ring slots per bin (flush granule 16; 16-slot slack)

#define NPX 3200000          // float pairs in x
#define NPW 24576            // float pairs in 3 weight mats
#define NPAIR (NPX + NPW)    // 3,224,576 -> 12,596 per block (exact)

typedef __attribute__((ext_vector_type(8))) short bf16x8;
typedef __attribute__((ext_vector_type(4))) float f32x4;

__device__ __forceinline__ float lrelu(float v) { return v >= 0.f ? v : NEG * v; }
__device__ __forceinline__ float bf_lo(unsigned u) { return __uint_as_float(u << 16); }
__device__ __forceinline__ float bf_hi(unsigned u) { return __uint_as_float(u & 0xffff0000u); }
__device__ __forceinline__ unsigned f2bf(float x) {          // RNE
    unsigned u = __float_as_uint(x);
    return (u + 0x7fffu + ((u >> 16) & 1u)) >> 16;
}
__device__ __forceinline__ unsigned packbf(float lo, float hi) {
    unsigned b = __float_as_uint(hi);
    b = (b + 0x7fffu + ((b >> 16) & 1u)) & 0xffff0000u;
    return (f2bf(lo) & 0xffffu) | b;
}
__device__ __forceinline__ void acc8(float* c, uint4 q) {
    c[0] += bf_lo(q.x); c[1] += bf_hi(q.x);
    c[2] += bf_lo(q.y); c[3] += bf_hi(q.y);
    c[4] += bf_lo(q.z); c[5] += bf_hi(q.z);
    c[6] += bf_lo(q.w); c[7] += bf_hi(q.w);
}

// ---------------- 1. FUSED prep (x/W -> bf16) + multisplit binning ----------------
// bin part is barrier/LDS-latency bound at 1 block/CU; the interleaved prep
// pairs (2/thread/batch) stream through the otherwise-idle memory pipe.
__global__ __launch_bounds__(256)
void prep_bin_kernel(const float* __restrict__ x, const float* __restrict__ Wrel,
                     const float* __restrict__ Wroot, const float* __restrict__ Wlin,
                     unsigned* __restrict__ xb2, unsigned* __restrict__ wb2,
                     const int* __restrict__ src, const int* __restrict__ dst,
                     int* __restrict__ bcnt, unsigned* __restrict__ recs, int n_edges)
{
    __shared__ __align__(16) unsigned buf[NBINS][RING];   // 100 KB (grid=1/CU: free)
    __shared__ int cnt[NBINS];
    __shared__ int flushed[NBINS];

    const int tid = threadIdx.x;
    for (int t = tid; t < NBINS; t += 256) { cnt[t] = 0; flushed[t] = 0; }
    __syncthreads();

    const int per = (n_edges + PH1B - 1) / PH1B;
    const int begin = blockIdx.x * per;
    const int end = min(begin + per, n_edges);

    const int pper = (NPAIR + PH1B - 1) / PH1B;           // 12596
    const int pbegin = blockIdx.x * pper;
    const int pend = min(pbegin + pper, NPAIR);
    int pi = 0;

    for (int base = begin; base < end; base += 256) {
        // interleaved prep: 2 pairs/thread/batch
        #pragma unroll
        for (int k = 0; k < 2; ++k) {
            int i = pbegin + pi + k * 256 + tid;
            if (i < pend) {
                if (i < NPX) {
                    float2 v = ((const float2*)x)[i];
                    xb2[i] = packbf(v.x, v.y);
                } else {
                    int j = i - NPX;
                    const float* W = (j < 8192) ? Wrel : (j < 16384 ? Wroot : Wlin);
                    float2 v = ((const float2*)W)[j & 8191];
                    wb2[j] = packbf(v.x, v.y);
                }
            }
        }
        pi += 512;

        int i = base + tid;
        if (i < end) {
            int s = src[i], d = dst[i];
            int b = d >> 6;
            unsigned rec = (unsigned)s | ((unsigned)(d & 63) << 16);
            int pos = atomicAdd(&cnt[b], 1);
            buf[b][pos & (RING - 1)] = rec;
        }
        __syncthreads();
        for (int t = tid; t < NBINS; t += 256) {
            int c = cnt[t];
            int f = flushed[t];
            while (c - f >= 16) {                    // 16 recs = 64B = 1 line
                int gbase = atomicAdd(&bcnt[t], 16);
                unsigned* dp = recs + (long)t * CAPG + gbase;
                int ro = f & (RING - 1);             // multiple of 16, no wrap
                #pragma unroll
                for (int k = 0; k < 4; ++k)
                    *(uint4*)(dp + k * 4) = *(uint4*)&buf[t][ro + k * 4];
                f += 16;
            }
            flushed[t] = f;
        }
        __syncthreads();
    }
    // prep tail (safety; normally empty: 25 batches x 512 = 12800 >= 12596)
    for (int i = pbegin + pi + tid; i < pend; i += 256) {
        if (i < NPX) {
            float2 v = ((const float2*)x)[i];
            xb2[i] = packbf(v.x, v.y);
        } else {
            int j = i - NPX;
            const float* W = (j < 8192) ? Wrel : (j < 16384 ? Wroot : Wlin);
            float2 v = ((const float2*)W)[j & 8191];
            wb2[j] = packbf(v.x, v.y);
        }
    }
    // drain leftovers (<16 per bin per block) — compact via reservation
    for (int t = tid; t < NBINS; t += 256) {
        int c = cnt[t], f = flushed[t];
        int n = c - f;
        if (n > 0) {
            int gbase = atomicAdd(&bcnt[t], n);
            unsigned* dp = recs + (long)t * CAPG + gbase;
            int ro = f & (RING - 1);
            for (int k = 0; k < n; ++k) dp[k] = buf[t][ro + k];
        }
    }
}

// ---------------- 2. FUSED per-bin aggregate + MLP + BN (exact R10) ----------------
__global__ __launch_bounds__(512, 6)
void agg_mlp_kernel(const unsigned* __restrict__ xb2, const unsigned* __restrict__ recs,
                    const int* __restrict__ bcnt, const unsigned short* __restrict__ wb,
                    const float* __restrict__ brel, const float* __restrict__ blin,
                    float* __restrict__ out, float* __restrict__ sums,
                    float* __restrict__ sumsq)
{
    __shared__ unsigned srec[CAPG];                       // 16 KB (later: BN scratch)
    __shared__ int cnt[BINSZ];
    __shared__ int pos[BINSZ];
    __shared__ int offs[BINSZ + 1];
    __shared__ __align__(16) unsigned short smA[BINSZ][136];  // 17.4 KB

    const int bin = blockIdx.x;
    const int tid = threadIdx.x;          // 0..511
    const int l = tid & 63, w = tid >> 6; // wave 0..7
    const int l15 = l & 15, kg = l >> 4;
    const int g16 = l >> 4, c16 = l & 15; // gather: record slot / row chunk

    if (tid < BINSZ) cnt[tid] = 0;
    __syncthreads();

    const int n = bcnt[bin];
    const unsigned* rp = recs + (long)bin * CAPG;

    // A1: histogram by local dst
    for (int i = tid; i < n; i += 512)
        atomicAdd(&cnt[(rp[i] >> 16) & 63], 1);
    __syncthreads();

    // A2: exclusive scan over 64 counters (wave 0)
    if (tid < 64) {
        int v = cnt[tid];
        int inc = v;
        #pragma unroll
        for (int d = 1; d < 64; d <<= 1) {
            int u = __shfl_up(inc, d);
            if (tid >= d) inc += u;
        }
        offs[tid] = inc - v;
        pos[tid] = inc - v;
        if (tid == 63) offs[64] = inc;
    }
    __syncthreads();

    // A3: scatter into dst-sorted order
    for (int i = tid; i < n; i += 512) {
        unsigned r = rp[i];
        int p = atomicAdd(&pos[(r >> 16) & 63], 1);
        srec[p] = r;
    }
    __syncthreads();

    // A4: per-node register accumulation, uint4 gather (4 records/load)
    unsigned* smA32 = (unsigned*)smA;
    for (int lo = w; lo < BINSZ; lo += 8) {
        const int b = offs[lo], e = offs[lo + 1];
        float c[8];
        #pragma unroll
        for (int k = 0; k < 8; ++k) c[k] = 0.f;

        int i = b;
        for (; i + 16 <= e; i += 16) {
            unsigned r0 = srec[i + g16];
            unsigned r1 = srec[i + 4 + g16];
            unsigned r2 = srec[i + 8 + g16];
            unsigned r3 = srec[i + 12 + g16];
            uint4 q0 = *((const uint4*)(xb2 + (r0 & 0xffffu) * 64) + c16);
            uint4 q1 = *((const uint4*)(xb2 + (r1 & 0xffffu) * 64) + c16);
            uint4 q2 = *((const uint4*)(xb2 + (r2 & 0xffffu) * 64) + c16);
            uint4 q3 = *((const uint4*)(xb2 + (r3 & 0xffffu) * 64) + c16);
            acc8(c, q0); acc8(c, q1); acc8(c, q2); acc8(c, q3);
        }
        for (; i + 4 <= e; i += 4) {
            unsigned r = srec[i + g16];
            uint4 q = *((const uint4*)(xb2 + (r & 0xffffu) * 64) + c16);
            acc8(c, q);
        }
        if (i < e) {                                   // 1..3 leftover records
            int idx = i + g16;
            if (idx < e) {
                unsigned r = srec[idx];
                uint4 q = *((const uint4*)(xb2 + (r & 0xffffu) * 64) + c16);
                acc8(c, q);
            }
        }
        // fold the 4 record slots
        #pragma unroll
        for (int k = 0; k < 8; ++k) {
            c[k] += __shfl_xor(c[k], 16);
            c[k] += __shfl_xor(c[k], 32);
        }
        if (l < 16) {
            uint4 o;
            o.x = packbf(c[0], c[1]); o.y = packbf(c[2], c[3]);
            o.z = packbf(c[4], c[5]); o.w = packbf(c[6], c[7]);
            *((uint4*)(smA32 + lo * 68) + c16) = o;
        }
    }
    __syncthreads();   // smA ready; srec reads complete (free for reuse)

    // ---- Phase B: MLP (8 waves: m = w&3 M-tile, ch = w>>2 col-half) ----
    const unsigned short* Wrelb  = wb;
    const unsigned short* Wrootb = wb + 16384;
    const unsigned short* Wlinb  = wb + 32768;
    const unsigned short* xbs = (const unsigned short*)xb2;

    const int m  = w & 3;
    const int ch = w >> 2;
    const int row = m * 16 + l15;
    const int gA = bin * 64 + row;
    const long gAc = min(gA, NNODES - 1);

    f32x4 acc[4];
    #pragma unroll
    for (int nt = 0; nt < 4; ++nt) acc[nt] = (f32x4){0.f, 0.f, 0.f, 0.f};

    #pragma unroll
    for (int s = 0; s < 8; ++s) {
        const int ko = (s & 3) * 32 + kg * 8;
        bf16x8 a;
        if (s < 4) a = *(const bf16x8*)&smA[row][ko];
        else       a = *(const bf16x8*)(xbs + gAc * 128 + ko);
        const unsigned short* Bb = (s < 4) ? Wrelb : Wrootb;
        #pragma unroll
        for (int nt = 0; nt < 4; ++nt) {
            bf16x8 b = *(const bf16x8*)(Bb + (ch * 64 + nt * 16 + l15) * 128 + ko);
            acc[nt] = __builtin_amdgcn_mfma_f32_16x16x32_bf16(a, b, acc[nt], 0, 0, 0);
        }
    }
    __syncthreads();   // stage-1 smA reads done before cross-wave x2 writes

    #pragma unroll
    for (int nt = 0; nt < 4; ++nt) {
        const int col = ch * 64 + nt * 16 + l15;
        const float br = brel[col];
        #pragma unroll
        for (int r = 0; r < 4; ++r) {
            smA[m * 16 + kg * 4 + r][col] =
                (unsigned short)f2bf(lrelu(acc[nt][r] + br));
        }
    }
    __syncthreads();

    f32x4 acc2[4];
    #pragma unroll
    for (int nt = 0; nt < 4; ++nt) acc2[nt] = (f32x4){0.f, 0.f, 0.f, 0.f};

    #pragma unroll
    for (int s = 0; s < 4; ++s) {
        const int ko = s * 32 + kg * 8;
        bf16x8 a = *(const bf16x8*)&smA[row][ko];
        #pragma unroll
        for (int nt = 0; nt < 4; ++nt) {
            bf16x8 b = *(const bf16x8*)(Wlinb + (ch * 64 + nt * 16 + l15) * 128 + ko);
            acc2[nt] = __builtin_amdgcn_mfma_f32_16x16x32_bf16(a, b, acc2[nt], 0, 0, 0);
        }
    }

    // epilogue: +blin, store fp32, BN partials via LDS (srec as scratch)
    float* redS = (float*)srec;   // [2 kinds][4 m][128 cols] = 4 KB
    #pragma unroll
    for (int nt = 0; nt < 4; ++nt) {
        const int col = ch * 64 + nt * 16 + l15;
        const float bl = blin[col];
        float ps = 0.f, pq = 0.f;
        #pragma unroll
        for (int r = 0; r < 4; ++r) {
            int g = bin * 64 + m * 16 + kg * 4 + r;
            if (g < NNODES) {
                float y = acc2[nt][r] + bl;
                out[(long)g * 128 + col] = y;
                ps += y; pq += y * y;
            }
        }
        ps += __shfl_xor(ps, 16); ps += __shfl_xor(ps, 32);
        pq += __shfl_xor(pq, 16); pq += __shfl_xor(pq, 32);
        if (kg == 0) {
            redS[(0 * 4 + m) * 128 + col] = ps;
            redS[(1 * 4 + m) * 128 + col] = pq;
        }
    }
    __syncthreads();
    if (tid < 128) {
        float s = redS[0 * 128 + tid] + redS[1 * 128 + tid]
                + redS[2 * 128 + tid] + redS[3 * 128 + tid];
        float q = redS[4 * 128 + tid] + redS[5 * 128 + tid]
                + redS[6 * 128 + tid] + redS[7 * 128 + tid];
        atomicAdd(&sums[tid], s);
        atomicAdd(&sumsq[tid], q);
    }
}

// ---------------- 3. BN finalize + apply + leaky (fused, in-place fp32) ----------------
__global__ __launch_bounds__(256)
void bn_apply_kernel(float* __restrict__ out,
                     const float* __restrict__ sums, const float* __restrict__ sumsq,
                     const float* __restrict__ gamma, const float* __restrict__ beta)
{
    __shared__ float s_sc[128], s_sh[128];
    if (threadIdx.x < 128) {
        int h = threadIdx.x;
        float mean = sums[h] * (1.f / NNODES);
        float var = sumsq[h] * (1.f / NNODES) - mean * mean;
        float sc = gamma[h] * rsqrtf(var + BN_EPS);
        s_sc[h] = sc;
        s_sh[h] = beta[h] - mean * sc;
    }
    __syncthreads();
    const int total = NNODES * 32;
    float4* o4 = (float4*)out;
    for (int i = blockIdx.x * 256 + threadIdx.x; i < total; i += gridDim.x * 256) {
        float4 v = o4[i];
        int h = (i & 31) * 4;
        v.x = lrelu(v.x * s_sc[h + 0] + s_sh[h + 0]);
        v.y = lrelu(v.y * s_sc[h + 1] + s_sh[h + 1]);
        v.z = lrelu(v.z * s_sc[h + 2] + s_sh[h + 2]);
        v.w = lrelu(v.w * s_sc[h + 3] + s_sh[h + 3]);
        o4[i] = v;
    }
}

extern "C" void kernel_launch(void* const* d_in, const int* in_sizes, int n_in,
                              void* d_out, int out_size, void* d_ws, size_t ws_size,
                              hipStream_t stream)
{
    const float* x     = (const float*)d_in[0];
    const int*   ei    = (const int*)d_in[1];
    const float* Wrel  = (const float*)d_in[3];
    const float* brel  = (const float*)d_in[4];
    const float* Wroot = (const float*)d_in[5];
    const float* Wlin  = (const float*)d_in[6];
    const float* blin  = (const float*)d_in[7];
    const float* gamma = (const float*)d_in[8];
    const float* beta  = (const float*)d_in[9];
    float* out = (float*)d_out;

    const int n_edges = in_sizes[1] / 2;
    const int* src = ei;
    const int* dst = ei + n_edges;

    // workspace layout (bytes):
    // xb    @ 0          : 12,800,000   (x as bf16)
    // recs  @ 12,800,000 : 12,812,288   (NBINS*CAPG*4)
    // wb    @ 25,612,288 : 98,304
    // bcnt  @ 25,710,592 : 3,128        } memset together (5,248 B)
    // stats @ 25,713,792 : 2,048        }   -> total 25.72 MB
    char* ws = (char*)d_ws;
    unsigned short* xb   = (unsigned short*)ws;
    unsigned*       recs = (unsigned*)(ws + 12800000);
    unsigned short* wb   = (unsigned short*)(ws + 25612288);
    int*   bcnt  = (int*)(ws + 25710592);
    float* sums  = (float*)(ws + 25713792);
    float* sumsq = sums + 128;

    hipMemsetAsync(bcnt, 0, 5248, stream);   // bcnt + stats

    prep_bin_kernel<<<PH1B, 256, 0, stream>>>(x, Wrel, Wroot, Wlin,
                                              (unsigned*)xb, (unsigned*)wb,
                                              src, dst, bcnt, recs, n_edges);
    agg_mlp_kernel<<<NBINS, 512, 0, stream>>>((const unsigned*)xb, recs, bcnt, wb,
                                              brel, blin, out, sums, sumsq);
    bn_apply_kernel<<<2048, 256, 0, stream>>>(out, sums, sumsq, gamma, beta);
}

// Round 15
// 153.003 us; speedup vs baseline: 1.5350x; 1.1033x over previous
//
#include <hip/hip_runtime.h>

#define NNODES 50000
#define NEG 0.01f
#define BN_EPS 1e-5f

#define BINSZ 64             // dst nodes per bin
#define NBINS 782            // ceil(50000/64)
#define CAPG 4096            // record capacity per bin (mean ~2046)
#define PH1B 256             // phase-1 blocks (1 per CU)
#define RING 32              // ring slots per bin (flush granule 16; 16-slot slack)
#define EPB 4                // edges per thread per batch (7 batches total)

typedef __attribute__((ext_vector_type(8))) short bf16x8;
typedef __attribute__((ext_vector_type(4))) float f32x4;

__device__ __forceinline__ float lrelu(float v) { return v >= 0.f ? v : NEG * v; }
__device__ __forceinline__ float bf_lo(unsigned u) { return __uint_as_float(u << 16); }
__device__ __forceinline__ float bf_hi(unsigned u) { return __uint_as_float(u & 0xffff0000u); }
__device__ __forceinline__ unsigned f2bf(float x) {          // RNE
    unsigned u = __float_as_uint(x);
    return (u + 0x7fffu + ((u >> 16) & 1u)) >> 16;
}
__device__ __forceinline__ unsigned packbf(float lo, float hi) {
    unsigned b = __float_as_uint(hi);
    b = (b + 0x7fffu + ((b >> 16) & 1u)) & 0xffff0000u;
    return (f2bf(lo) & 0xffffu) | b;
}
__device__ __forceinline__ void acc8(float* c, uint4 q) {
    c[0] += bf_lo(q.x); c[1] += bf_hi(q.x);
    c[2] += bf_lo(q.y); c[3] += bf_hi(q.y);
    c[4] += bf_lo(q.z); c[5] += bf_hi(q.z);
    c[6] += bf_lo(q.w); c[7] += bf_hi(q.w);
}

// ---------------- 0. convert x + weights to bf16 (standalone, proven) ----------------
__global__ __launch_bounds__(256)
void prep_kernel(const float* __restrict__ x, const float* __restrict__ Wrel,
                 const float* __restrict__ Wroot, const float* __restrict__ Wlin,
                 unsigned* __restrict__ xb2, unsigned* __restrict__ wb2)
{
    const int NPX = 3200000;           // float pairs in x
    const int NPW = 24576;             // float pairs in 3 weight mats
    for (int i = blockIdx.x * 256 + threadIdx.x; i < NPX + NPW; i += gridDim.x * 256) {
        if (i < NPX) {
            float2 v = ((const float2*)x)[i];
            xb2[i] = packbf(v.x, v.y);
        } else {
            int j = i - NPX;
            const float* W = (j < 8192) ? Wrel : (j < 16384 ? Wroot : Wlin);
            float2 v = ((const float2*)W)[j & 8191];
            wb2[j] = packbf(v.x, v.y);
        }
    }
}

// ---------------- 1. multisplit: 4 edges/thread/batch -> 7 batches (1/4 barriers) ----------------
__global__ __launch_bounds__(256)
void bin_kernel(const int* __restrict__ src, const int* __restrict__ dst,
                int* __restrict__ bcnt, unsigned* __restrict__ recs, int n_edges)
{
    __shared__ __align__(16) unsigned buf[NBINS][RING];   // 100 KB (grid=1/CU: free)
    __shared__ int cnt[NBINS];
    __shared__ int flushed[NBINS];

    const int tid = threadIdx.x;
    for (int t = tid; t < NBINS; t += 256) { cnt[t] = 0; flushed[t] = 0; }
    __syncthreads();

    const int per = (n_edges + PH1B - 1) / PH1B;          // 6250
    const int begin = blockIdx.x * per;
    const int end = min(begin + per, n_edges);

    for (int base = begin; base < end; base += 256 * EPB) {
        #pragma unroll
        for (int k = 0; k < EPB; ++k) {
            int i = base + k * 256 + tid;
            if (i < end) {
                int s = src[i], d = dst[i];
                int b = d >> 6;
                unsigned rec = (unsigned)s | ((unsigned)(d & 63) << 16);
                int pos = atomicAdd(&cnt[b], 1);
                buf[b][pos & (RING - 1)] = rec;
            }
        }
        __syncthreads();
        for (int t = tid; t < NBINS; t += 256) {
            int c = cnt[t];
            int f = flushed[t];
            while (c - f >= 16) {                    // 16 recs = 64B = 1 line
                int gbase = atomicAdd(&bcnt[t], 16);
                unsigned* dp = recs + (long)t * CAPG + gbase;
                int ro = f & (RING - 1);             // multiple of 16, no wrap
                #pragma unroll
                for (int k = 0; k < 4; ++k)
                    *(uint4*)(dp + k * 4) = *(uint4*)&buf[t][ro + k * 4];
                f += 16;
            }
            flushed[t] = f;
        }
        __syncthreads();
    }
    // drain leftovers (<16 per bin per block) — compact via reservation
    for (int t = tid; t < NBINS; t += 256) {
        int c = cnt[t], f = flushed[t];
        int n = c - f;
        if (n > 0) {
            int gbase = atomicAdd(&bcnt[t], n);
            unsigned* dp = recs + (long)t * CAPG + gbase;
            int ro = f & (RING - 1);
            for (int k = 0; k < n; ++k) dp[k] = buf[t][ro + k];
        }
    }
}

// ---------------- 2. FUSED per-bin aggregate + MLP + BN (exact R10/R14) ----------------
__global__ __launch_bounds__(512, 6)
void agg_mlp_kernel(const unsigned* __restrict__ xb2, const unsigned* __restrict__ recs,
                    const int* __restrict__ bcnt, const unsigned short* __restrict__ wb,
                    const float* __restrict__ brel, const float* __restrict__ blin,
                    float* __restrict__ out, float* __restrict__ sums,
                    float* __restrict__ sumsq)
{
    __shared__ unsigned srec[CAPG];                       // 16 KB (later: BN scratch)
    __shared__ int cnt[BINSZ];
    __shared__ int pos[BINSZ];
    __shared__ int offs[BINSZ + 1];
    __shared__ __align__(16) unsigned short smA[BINSZ][136];  // 17.4 KB

    const int bin = blockIdx.x;
    const int tid = threadIdx.x;          // 0..511
    const int l = tid & 63, w = tid >> 6; // wave 0..7
    const int l15 = l & 15, kg = l >> 4;
    const int g16 = l >> 4, c16 = l & 15; // gather: record slot / row chunk

    if (tid < BINSZ) cnt[tid] = 0;
    __syncthreads();

    const int n = bcnt[bin];
    const unsigned* rp = recs + (long)bin * CAPG;

    // A1: histogram by local dst
    for (int i = tid; i < n; i += 512)
        atomicAdd(&cnt[(rp[i] >> 16) & 63], 1);
    __syncthreads();

    // A2: exclusive scan over 64 counters (wave 0)
    if (tid < 64) {
        int v = cnt[tid];
        int inc = v;
        #pragma unroll
        for (int d = 1; d < 64; d <<= 1) {
            int u = __shfl_up(inc, d);
            if (tid >= d) inc += u;
        }
        offs[tid] = inc - v;
        pos[tid] = inc - v;
        if (tid == 63) offs[64] = inc;
    }
    __syncthreads();

    // A3: scatter into dst-sorted order
    for (int i = tid; i < n; i += 512) {
        unsigned r = rp[i];
        int p = atomicAdd(&pos[(r >> 16) & 63], 1);
        srec[p] = r;
    }
    __syncthreads();

    // A4: per-node register accumulation, uint4 gather (4 records/load)
    unsigned* smA32 = (unsigned*)smA;
    for (int lo = w; lo < BINSZ; lo += 8) {
        const int b = offs[lo], e = offs[lo + 1];
        float c[8];
        #pragma unroll
        for (int k = 0; k < 8; ++k) c[k] = 0.f;

        int i = b;
        for (; i + 16 <= e; i += 16) {
            unsigned r0 = srec[i + g16];
            unsigned r1 = srec[i + 4 + g16];
            unsigned r2 = srec[i + 8 + g16];
            unsigned r3 = srec[i + 12 + g16];
            uint4 q0 = *((const uint4*)(xb2 + (r0 & 0xffffu) * 64) + c16);
            uint4 q1 = *((const uint4*)(xb2 + (r1 & 0xffffu) * 64) + c16);
            uint4 q2 = *((const uint4*)(xb2 + (r2 & 0xffffu) * 64) + c16);
            uint4 q3 = *((const uint4*)(xb2 + (r3 & 0xffffu) * 64) + c16);
            acc8(c, q0); acc8(c, q1); acc8(c, q2); acc8(c, q3);
        }
        for (; i + 4 <= e; i += 4) {
            unsigned r = srec[i + g16];
            uint4 q = *((const uint4*)(xb2 + (r & 0xffffu) * 64) + c16);
            acc8(c, q);
        }
        if (i < e) {                                   // 1..3 leftover records
            int idx = i + g16;
            if (idx < e) {
                unsigned r = srec[idx];
                uint4 q = *((const uint4*)(xb2 + (r & 0xffffu) * 64) + c16);
                acc8(c, q);
            }
        }
        // fold the 4 record slots
        #pragma unroll
        for (int k = 0; k < 8; ++k) {
            c[k] += __shfl_xor(c[k], 16);
            c[k] += __shfl_xor(c[k], 32);
        }
        if (l < 16) {
            uint4 o;
            o.x = packbf(c[0], c[1]); o.y = packbf(c[2], c[3]);
            o.z = packbf(c[4], c[5]); o.w = packbf(c[6], c[7]);
            *((uint4*)(smA32 + lo * 68) + c16) = o;
        }
    }
    __syncthreads();   // smA ready; srec reads complete (free for reuse)

    // ---- Phase B: MLP (8 waves: m = w&3 M-tile, ch = w>>2 col-half) ----
    const unsigned short* Wrelb  = wb;
    const unsigned short* Wrootb = wb + 16384;
    const unsigned short* Wlinb  = wb + 32768;
    const unsigned short* xbs = (const unsigned short*)xb2;

    const int m  = w & 3;
    const int ch = w >> 2;
    const int row = m * 16 + l15;
    const int gA = bin * 64 + row;
    const long gAc = min(gA, NNODES - 1);

    f32x4 acc[4];
    #pragma unroll
    for (int nt = 0; nt < 4; ++nt) acc[nt] = (f32x4){0.f, 0.f, 0.f, 0.f};

    #pragma unroll
    for (int s = 0; s < 8; ++s) {
        const int ko = (s & 3) * 32 + kg * 8;
        bf16x8 a;
        if (s < 4) a = *(const bf16x8*)&smA[row][ko];
        else       a = *(const bf16x8*)(xbs + gAc * 128 + ko);
        const unsigned short* Bb = (s < 4) ? Wrelb : Wrootb;
        #pragma unroll
        for (int nt = 0; nt < 4; ++nt) {
            bf16x8 b = *(const bf16x8*)(Bb + (ch * 64 + nt * 16 + l15) * 128 + ko);
            acc[nt] = __builtin_amdgcn_mfma_f32_16x16x32_bf16(a, b, acc[nt], 0, 0, 0);
        }
    }
    __syncthreads();   // stage-1 smA reads done before cross-wave x2 writes

    #pragma unroll
    for (int nt = 0; nt < 4; ++nt) {
        const int col = ch * 64 + nt * 16 + l15;
        const float br = brel[col];
        #pragma unroll
        for (int r = 0; r < 4; ++r) {
            smA[m * 16 + kg * 4 + r][col] =
                (unsigned short)f2bf(lrelu(acc[nt][r] + br));
        }
    }
    __syncthreads();

    f32x4 acc2[4];
    #pragma unroll
    for (int nt = 0; nt < 4; ++nt) acc2[nt] = (f32x4){0.f, 0.f, 0.f, 0.f};

    #pragma unroll
    for (int s = 0; s < 4; ++s) {
        const int ko = s * 32 + kg * 8;
        bf16x8 a = *(const bf16x8*)&smA[row][ko];
        #pragma unroll
        for (int nt = 0; nt < 4; ++nt) {
            bf16x8 b = *(const bf16x8*)(Wlinb + (ch * 64 + nt * 16 + l15) * 128 + ko);
            acc2[nt] = __builtin_amdgcn_mfma_f32_16x16x32_bf16(a, b, acc2[nt], 0, 0, 0);
        }
    }

    // epilogue: +blin, store fp32, BN partials via LDS (srec as scratch)
    float* redS = (float*)srec;   // [2 kinds][4 m][128 cols] = 4 KB
    #pragma unroll
    for (int nt = 0; nt < 4; ++nt) {
        const int col = ch * 64 + nt * 16 + l15;
        const float bl = blin[col];
        float ps = 0.f, pq = 0.f;
        #pragma unroll
        for (int r = 0; r < 4; ++r) {
            int g = bin * 64 + m * 16 + kg * 4 + r;
            if (g < NNODES) {
                float y = acc2[nt][r] + bl;
                out[(long)g * 128 + col] = y;
                ps += y; pq += y * y;
            }
        }
        ps += __shfl_xor(ps, 16); ps += __shfl_xor(ps, 32);
        pq += __shfl_xor(pq, 16); pq += __shfl_xor(pq, 32);
        if (kg == 0) {
            redS[(0 * 4 + m) * 128 + col] = ps;
            redS[(1 * 4 + m) * 128 + col] = pq;
        }
    }
    __syncthreads();
    if (tid < 128) {
        float s = redS[0 * 128 + tid] + redS[1 * 128 + tid]
                + redS[2 * 128 + tid] + redS[3 * 128 + tid];
        float q = redS[4 * 128 + tid] + redS[5 * 128 + tid]
                + redS[6 * 128 + tid] + redS[7 * 128 + tid];
        atomicAdd(&sums[tid], s);
        atomicAdd(&sumsq[tid], q);
    }
}

// ---------------- 3. BN finalize + apply + leaky (fused, in-place fp32) ----------------
__global__ __launch_bounds__(256)
void bn_apply_kernel(float* __restrict__ out,
                     const float* __restrict__ sums, const float* __restrict__ sumsq,
                     const float* __restrict__ gamma, const float* __restrict__ beta)
{
    __shared__ float s_sc[128], s_sh[128];
    if (threadIdx.x < 128) {
        int h = threadIdx.x;
        float mean = sums[h] * (1.f / NNODES);
        float var = sumsq[h] * (1.f / NNODES) - mean * mean;
        float sc = gamma[h] * rsqrtf(var + BN_EPS);
        s_sc[h] = sc;
        s_sh[h] = beta[h] - mean * sc;
    }
    __syncthreads();
    const int total = NNODES * 32;
    float4* o4 = (float4*)out;
    for (int i = blockIdx.x * 256 + threadIdx.x; i < total; i += gridDim.x * 256) {
        float4 v = o4[i];
        int h = (i & 31) * 4;
        v.x = lrelu(v.x * s_sc[h + 0] + s_sh[h + 0]);
        v.y = lrelu(v.y * s_sc[h + 1] + s_sh[h + 1]);
        v.z = lrelu(v.z * s_sc[h + 2] + s_sh[h + 2]);
        v.w = lrelu(v.w * s_sc[h + 3] + s_sh[h + 3]);
        o4[i] = v;
    }
}

extern "C" void kernel_launch(void* const* d_in, const int* in_sizes, int n_in,
                              void* d_out, int out_size, void* d_ws, size_t ws_size,
                              hipStream_t stream)
{
    const float* x     = (const float*)d_in[0];
    const int*   ei    = (const int*)d_in[1];
    const float* Wrel  = (const float*)d_in[3];
    const float* brel  = (const float*)d_in[4];
    const float* Wroot = (const float*)d_in[5];
    const float* Wlin  = (const float*)d_in[6];
    const float* blin  = (const float*)d_in[7];
    const float* gamma = (const float*)d_in[8];
    const float* beta  = (const float*)d_in[9];
    float* out = (float*)d_out;

    const int n_edges = in_sizes[1] / 2;
    const int* src = ei;
    const int* dst = ei + n_edges;

    // workspace layout (bytes):
    // xb    @ 0          : 12,800,000   (x as bf16)
    // recs  @ 12,800,000 : 12,812,288   (NBINS*CAPG*4)
    // wb    @ 25,612,288 : 98,304
    // bcnt  @ 25,710,592 : 3,128        } memset together (5,248 B)
    // stats @ 25,713,792 : 2,048        }   -> total 25.72 MB
    char* ws = (char*)d_ws;
    unsigned short* xb   = (unsigned short*)ws;
    unsigned*       recs = (unsigned*)(ws + 12800000);
    unsigned short* wb   = (unsigned short*)(ws + 25612288);
    int*   bcnt  = (int*)(ws + 25710592);
    float* sums  = (float*)(ws + 25713792);
    float* sumsq = sums + 128;

    hipMemsetAsync(bcnt, 0, 5248, stream);   // bcnt + stats

    prep_kernel<<<4096, 256, 0, stream>>>(x, Wrel, Wroot, Wlin, (unsigned*)xb, (unsigned*)wb);
    bin_kernel<<<PH1B, 256, 0, stream>>>(src, dst, bcnt, recs, n_edges);
    agg_mlp_kernel<<<NBINS, 512, 0, stream>>>((const unsigned*)xb, recs, bcnt, wb,
                                              brel, blin, out, sums, sumsq);
    bn_apply_kernel<<<2048, 256, 0, stream>>>(out, sums, sumsq, gamma, beta);
}

// Round 16
// 146.768 us; speedup vs baseline: 1.6002x; 1.0425x over previous
//
#include <hip/hip_runtime.h>

#define NNODES 50000
#define NEG 0.01f
#define BN_EPS 1e-5f

#define BINSZ 64             // dst nodes per bin
#define NBINS 782            // ceil(50000/64)
#define CAPG 4096            // record capacity per bin (mean ~2046)
#define PH1B 256             // phase-1 blocks (1 per CU)
#define RING 32              // ring slots per bin (flush granule 16; 16-slot slack)
#define EPB 8                // edges per thread per batch (4 batches total)

typedef __attribute__((ext_vector_type(8))) short bf16x8;
typedef __attribute__((ext_vector_type(4))) float f32x4;

__device__ __forceinline__ float lrelu(float v) { return v >= 0.f ? v : NEG * v; }
__device__ __forceinline__ float bf_lo(unsigned u) { return __uint_as_float(u << 16); }
__device__ __forceinline__ float bf_hi(unsigned u) { return __uint_as_float(u & 0xffff0000u); }
__device__ __forceinline__ unsigned f2bf(float x) {          // RNE
    unsigned u = __float_as_uint(x);
    return (u + 0x7fffu + ((u >> 16) & 1u)) >> 16;
}
__device__ __forceinline__ unsigned packbf(float lo, float hi) {
    unsigned b = __float_as_uint(hi);
    b = (b + 0x7fffu + ((b >> 16) & 1u)) & 0xffff0000u;
    return (f2bf(lo) & 0xffffu) | b;
}
__device__ __forceinline__ void acc8(float* c, uint4 q) {
    c[0] += bf_lo(q.x); c[1] += bf_hi(q.x);
    c[2] += bf_lo(q.y); c[3] += bf_hi(q.y);
    c[4] += bf_lo(q.z); c[5] += bf_hi(q.z);
    c[6] += bf_lo(q.w); c[7] += bf_hi(q.w);
}

// ---------------- 0. convert x + weights to bf16; block 0 zeroes bcnt+stats ----------------
__global__ __launch_bounds__(256)
void prep_kernel(const float* __restrict__ x, const float* __restrict__ Wrel,
                 const float* __restrict__ Wroot, const float* __restrict__ Wlin,
                 unsigned* __restrict__ xb2, unsigned* __restrict__ wb2,
                 unsigned* __restrict__ zero_region)   // bcnt..stats, 1312 uints
{
    if (blockIdx.x == 0) {
        for (int i = threadIdx.x; i < 1312; i += 256) zero_region[i] = 0u;
    }
    const int NPX = 3200000;           // float pairs in x
    const int NPW = 24576;             // float pairs in 3 weight mats
    for (int i = blockIdx.x * 256 + threadIdx.x; i < NPX + NPW; i += gridDim.x * 256) {
        if (i < NPX) {
            float2 v = ((const float2*)x)[i];
            xb2[i] = packbf(v.x, v.y);
        } else {
            int j = i - NPX;
            const float* W = (j < 8192) ? Wrel : (j < 16384 ? Wroot : Wlin);
            float2 v = ((const float2*)W)[j & 8191];
            wb2[j] = packbf(v.x, v.y);
        }
    }
}

// ---------------- 1. multisplit: 8 edges/thread/batch -> 4 batches ----------------
__global__ __launch_bounds__(256)
void bin_kernel(const int* __restrict__ src, const int* __restrict__ dst,
                int* __restrict__ bcnt, unsigned* __restrict__ recs, int n_edges)
{
    __shared__ __align__(16) unsigned buf[NBINS][RING];   // 100 KB (grid=1/CU: free)
    __shared__ int cnt[NBINS];
    __shared__ int flushed[NBINS];

    const int tid = threadIdx.x;
    for (int t = tid; t < NBINS; t += 256) { cnt[t] = 0; flushed[t] = 0; }
    __syncthreads();

    const int per = (n_edges + PH1B - 1) / PH1B;          // 6250
    const int begin = blockIdx.x * per;
    const int end = min(begin + per, n_edges);

    for (int base = begin; base < end; base += 256 * EPB) {
        #pragma unroll
        for (int k = 0; k < EPB; ++k) {
            int i = base + k * 256 + tid;
            if (i < end) {
                int s = src[i], d = dst[i];
                int b = d >> 6;
                unsigned rec = (unsigned)s | ((unsigned)(d & 63) << 16);
                int pos = atomicAdd(&cnt[b], 1);
                buf[b][pos & (RING - 1)] = rec;
            }
        }
        __syncthreads();
        for (int t = tid; t < NBINS; t += 256) {
            int c = cnt[t];
            int f = flushed[t];
            while (c - f >= 16) {                    // 16 recs = 64B = 1 line
                int gbase = atomicAdd(&bcnt[t], 16);
                unsigned* dp = recs + (long)t * CAPG + gbase;
                int ro = f & (RING - 1);             // multiple of 16, no wrap
                #pragma unroll
                for (int k = 0; k < 4; ++k)
                    *(uint4*)(dp + k * 4) = *(uint4*)&buf[t][ro + k * 4];
                f += 16;
            }
            flushed[t] = f;
        }
        __syncthreads();
    }
    // drain leftovers (<16 per bin per block) — compact via reservation
    for (int t = tid; t < NBINS; t += 256) {
        int c = cnt[t], f = flushed[t];
        int n = c - f;
        if (n > 0) {
            int gbase = atomicAdd(&bcnt[t], n);
            unsigned* dp = recs + (long)t * CAPG + gbase;
            int ro = f & (RING - 1);
            for (int k = 0; k < n; ++k) dp[k] = buf[t][ro + k];
        }
    }
}

// ---------------- 2. FUSED per-bin aggregate + MLP + BN (exact R10/R14/R15) ----------------
__global__ __launch_bounds__(512, 6)
void agg_mlp_kernel(const unsigned* __restrict__ xb2, const unsigned* __restrict__ recs,
                    const int* __restrict__ bcnt, const unsigned short* __restrict__ wb,
                    const float* __restrict__ brel, const float* __restrict__ blin,
                    float* __restrict__ out, float* __restrict__ sums,
                    float* __restrict__ sumsq)
{
    __shared__ unsigned srec[CAPG];                       // 16 KB (later: BN scratch)
    __shared__ int cnt[BINSZ];
    __shared__ int pos[BINSZ];
    __shared__ int offs[BINSZ + 1];
    __shared__ __align__(16) unsigned short smA[BINSZ][136];  // 17.4 KB

    const int bin = blockIdx.x;
    const int tid = threadIdx.x;          // 0..511
    const int l = tid & 63, w = tid >> 6; // wave 0..7
    const int l15 = l & 15, kg = l >> 4;
    const int g16 = l >> 4, c16 = l & 15; // gather: record slot / row chunk

    if (tid < BINSZ) cnt[tid] = 0;
    __syncthreads();

    const int n = bcnt[bin];
    const unsigned* rp = recs + (long)bin * CAPG;

    // A1: histogram by local dst
    for (int i = tid; i < n; i += 512)
        atomicAdd(&cnt[(rp[i] >> 16) & 63], 1);
    __syncthreads();

    // A2: exclusive scan over 64 counters (wave 0)
    if (tid < 64) {
        int v = cnt[tid];
        int inc = v;
        #pragma unroll
        for (int d = 1; d < 64; d <<= 1) {
            int u = __shfl_up(inc, d);
            if (tid >= d) inc += u;
        }
        offs[tid] = inc - v;
        pos[tid] = inc - v;
        if (tid == 63) offs[64] = inc;
    }
    __syncthreads();

    // A3: scatter into dst-sorted order
    for (int i = tid; i < n; i += 512) {
        unsigned r = rp[i];
        int p = atomicAdd(&pos[(r >> 16) & 63], 1);
        srec[p] = r;
    }
    __syncthreads();

    // A4: per-node register accumulation, uint4 gather (4 records/load)
    unsigned* smA32 = (unsigned*)smA;
    for (int lo = w; lo < BINSZ; lo += 8) {
        const int b = offs[lo], e = offs[lo + 1];
        float c[8];
        #pragma unroll
        for (int k = 0; k < 8; ++k) c[k] = 0.f;

        int i = b;
        for (; i + 16 <= e; i += 16) {
            unsigned r0 = srec[i + g16];
            unsigned r1 = srec[i + 4 + g16];
            unsigned r2 = srec[i + 8 + g16];
            unsigned r3 = srec[i + 12 + g16];
            uint4 q0 = *((const uint4*)(xb2 + (r0 & 0xffffu) * 64) + c16);
            uint4 q1 = *((const uint4*)(xb2 + (r1 & 0xffffu) * 64) + c16);
            uint4 q2 = *((const uint4*)(xb2 + (r2 & 0xffffu) * 64) + c16);
            uint4 q3 = *((const uint4*)(xb2 + (r3 & 0xffffu) * 64) + c16);
            acc8(c, q0); acc8(c, q1); acc8(c, q2); acc8(c, q3);
        }
        for (; i + 4 <= e; i += 4) {
            unsigned r = srec[i + g16];
            uint4 q = *((const uint4*)(xb2 + (r & 0xffffu) * 64) + c16);
            acc8(c, q);
        }
        if (i < e) {                                   // 1..3 leftover records
            int idx = i + g16;
            if (idx < e) {
                unsigned r = srec[idx];
                uint4 q = *((const uint4*)(xb2 + (r & 0xffffu) * 64) + c16);
                acc8(c, q);
            }
        }
        // fold the 4 record slots
        #pragma unroll
        for (int k = 0; k < 8; ++k) {
            c[k] += __shfl_xor(c[k], 16);
            c[k] += __shfl_xor(c[k], 32);
        }
        if (l < 16) {
            uint4 o;
            o.x = packbf(c[0], c[1]); o.y = packbf(c[2], c[3]);
            o.z = packbf(c[4], c[5]); o.w = packbf(c[6], c[7]);
            *((uint4*)(smA32 + lo * 68) + c16) = o;
        }
    }
    __syncthreads();   // smA ready; srec reads complete (free for reuse)

    // ---- Phase B: MLP (8 waves: m = w&3 M-tile, ch = w>>2 col-half) ----
    const unsigned short* Wrelb  = wb;
    const unsigned short* Wrootb = wb + 16384;
    const unsigned short* Wlinb  = wb + 32768;
    const unsigned short* xbs = (const unsigned short*)xb2;

    const int m  = w & 3;
    const int ch = w >> 2;
    const int row = m * 16 + l15;
    const int gA = bin * 64 + row;
    const long gAc = min(gA, NNODES - 1);

    f32x4 acc[4];
    #pragma unroll
    for (int nt = 0; nt < 4; ++nt) acc[nt] = (f32x4){0.f, 0.f, 0.f, 0.f};

    #pragma unroll
    for (int s = 0; s < 8; ++s) {
        const int ko = (s & 3) * 32 + kg * 8;
        bf16x8 a;
        if (s < 4) a = *(const bf16x8*)&smA[row][ko];
        else       a = *(const bf16x8*)(xbs + gAc * 128 + ko);
        const unsigned short* Bb = (s < 4) ? Wrelb : Wrootb;
        #pragma unroll
        for (int nt = 0; nt < 4; ++nt) {
            bf16x8 b = *(const bf16x8*)(Bb + (ch * 64 + nt * 16 + l15) * 128 + ko);
            acc[nt] = __builtin_amdgcn_mfma_f32_16x16x32_bf16(a, b, acc[nt], 0, 0, 0);
        }
    }
    __syncthreads();   // stage-1 smA reads done before cross-wave x2 writes

    #pragma unroll
    for (int nt = 0; nt < 4; ++nt) {
        const int col = ch * 64 + nt * 16 + l15;
        const float br = brel[col];
        #pragma unroll
        for (int r = 0; r < 4; ++r) {
            smA[m * 16 + kg * 4 + r][col] =
                (unsigned short)f2bf(lrelu(acc[nt][r] + br));
        }
    }
    __syncthreads();

    f32x4 acc2[4];
    #pragma unroll
    for (int nt = 0; nt < 4; ++nt) acc2[nt] = (f32x4){0.f, 0.f, 0.f, 0.f};

    #pragma unroll
    for (int s = 0; s < 4; ++s) {
        const int ko = s * 32 + kg * 8;
        bf16x8 a = *(const bf16x8*)&smA[row][ko];
        #pragma unroll
        for (int nt = 0; nt < 4; ++nt) {
            bf16x8 b = *(const bf16x8*)(Wlinb + (ch * 64 + nt * 16 + l15) * 128 + ko);
            acc2[nt] = __builtin_amdgcn_mfma_f32_16x16x32_bf16(a, b, acc2[nt], 0, 0, 0);
        }
    }

    // epilogue: +blin, store fp32, BN partials via LDS (srec as scratch)
    float* redS = (float*)srec;   // [2 kinds][4 m][128 cols] = 4 KB
    #pragma unroll
    for (int nt = 0; nt < 4; ++nt) {
        const int col = ch * 64 + nt * 16 + l15;
        const float bl = blin[col];
        float ps = 0.f, pq = 0.f;
        #pragma unroll
        for (int r = 0; r < 4; ++r) {
            int g = bin * 64 + m * 16 + kg * 4 + r;
            if (g < NNODES) {
                float y = acc2[nt][r] + bl;
                out[(long)g * 128 + col] = y;
                ps += y; pq += y * y;
            }
        }
        ps += __shfl_xor(ps, 16); ps += __shfl_xor(ps, 32);
        pq += __shfl_xor(pq, 16); pq += __shfl_xor(pq, 32);
        if (kg == 0) {
            redS[(0 * 4 + m) * 128 + col] = ps;
            redS[(1 * 4 + m) * 128 + col] = pq;
        }
    }
    __syncthreads();
    if (tid < 128) {
        float s = redS[0 * 128 + tid] + redS[1 * 128 + tid]
                + redS[2 * 128 + tid] + redS[3 * 128 + tid];
        float q = redS[4 * 128 + tid] + redS[5 * 128 + tid]
                + redS[6 * 128 + tid] + redS[7 * 128 + tid];
        atomicAdd(&sums[tid], s);
        atomicAdd(&sumsq[tid], q);
    }
}

// ---------------- 3. BN finalize + apply + leaky (fused, in-place fp32) ----------------
__global__ __launch_bounds__(256)
void bn_apply_kernel(float* __restrict__ out,
                     const float* __restrict__ sums, const float* __restrict__ sumsq,
                     const float* __restrict__ gamma, const float* __restrict__ beta)
{
    __shared__ float s_sc[128], s_sh[128];
    if (threadIdx.x < 128) {
        int h = threadIdx.x;
        float mean = sums[h] * (1.f / NNODES);
        float var = sumsq[h] * (1.f / NNODES) - mean * mean;
        float sc = gamma[h] * rsqrtf(var + BN_EPS);
        s_sc[h] = sc;
        s_sh[h] = beta[h] - mean * sc;
    }
    __syncthreads();
    const int total = NNODES * 32;
    float4* o4 = (float4*)out;
    for (int i = blockIdx.x * 256 + threadIdx.x; i < total; i += gridDim.x * 256) {
        float4 v = o4[i];
        int h = (i & 31) * 4;
        v.x = lrelu(v.x * s_sc[h + 0] + s_sh[h + 0]);
        v.y = lrelu(v.y * s_sc[h + 1] + s_sh[h + 1]);
        v.z = lrelu(v.z * s_sc[h + 2] + s_sh[h + 2]);
        v.w = lrelu(v.w * s_sc[h + 3] + s_sh[h + 3]);
        o4[i] = v;
    }
}

extern "C" void kernel_launch(void* const* d_in, const int* in_sizes, int n_in,
                              void* d_out, int out_size, void* d_ws, size_t ws_size,
                              hipStream_t stream)
{
    const float* x     = (const float*)d_in[0];
    const int*   ei    = (const int*)d_in[1];
    const float* Wrel  = (const float*)d_in[3];
    const float* brel  = (const float*)d_in[4];
    const float* Wroot = (const float*)d_in[5];
    const float* Wlin  = (const float*)d_in[6];
    const float* blin  = (const float*)d_in[7];
    const float* gamma = (const float*)d_in[8];
    const float* beta  = (const float*)d_in[9];
    float* out = (float*)d_out;

    const int n_edges = in_sizes[1] / 2;
    const int* src = ei;
    const int* dst = ei + n_edges;

    // workspace layout (bytes):
    // xb    @ 0          : 12,800,000   (x as bf16)
    // recs  @ 12,800,000 : 12,812,288   (NBINS*CAPG*4)
    // wb    @ 25,612,288 : 98,304
    // bcnt  @ 25,710,592 : 3,128        } zeroed by prep block 0 (5,248 B)
    // stats @ 25,713,792 : 2,048        }   -> total 25.72 MB
    char* ws = (char*)d_ws;
    unsigned short* xb   = (unsigned short*)ws;
    unsigned*       recs = (unsigned*)(ws + 12800000);
    unsigned short* wb   = (unsigned short*)(ws + 25612288);
    int*   bcnt  = (int*)(ws + 25710592);
    float* sums  = (float*)(ws + 25713792);
    float* sumsq = sums + 128;

    prep_kernel<<<4096, 256, 0, stream>>>(x, Wrel, Wroot, Wlin,
                                          (unsigned*)xb, (unsigned*)wb, (unsigned*)bcnt);
    bin_kernel<<<PH1B, 256, 0, stream>>>(src, dst, bcnt, recs, n_edges);
    agg_mlp_kernel<<<NBINS, 512, 0, stream>>>((const unsigned*)xb, recs, bcnt, wb,
                                              brel, blin, out, sums, sumsq);
    bn_apply_kernel<<<2048, 256, 0, stream>>>(out, sums, sumsq, gamma, beta);
}